// Round 3
// baseline (9145.617 us; speedup 1.0000x reference)
//
#include <hip/hip_runtime.h>
#include <math.h>

#define B_  32
#define T_  512
#define H_  1024
#define NH_ 16
#define HD_ 64
#define FF_ 4096
#define BT_ (B_*T_)   // 16384
#define CB_ 8                 // batches per chunk
#define CR_ (CB_*T_)          // rows per chunk = 4096
#define NC_ (B_/CB_)          // 4 chunks

// ======================= LayerNorm stats =======================
// one block (256 thr) per row of 1024 floats; writes mu, rstd
__global__ __launch_bounds__(256) void ln_stats_kernel(const float* __restrict__ x,
    float* __restrict__ stats)
{
  const int row = blockIdx.x;
  const int tid = threadIdx.x;
  const float4 v = ((const float4*)(x + (size_t)row*H_))[tid];
  float s  = v.x+v.y+v.z+v.w;
  float ss = v.x*v.x+v.y*v.y+v.z*v.z+v.w*v.w;
  #pragma unroll
  for(int off=32; off>0; off>>=1){
    s  += __shfl_down(s, off);
    ss += __shfl_down(ss, off);
  }
  __shared__ float rs[4], rss[4];
  const int wave = tid>>6, lane = tid&63;
  if(lane==0){ rs[wave]=s; rss[wave]=ss; }
  __syncthreads();
  if(tid==0){
    float S  = rs[0]+rs[1]+rs[2]+rs[3];
    float SS = rss[0]+rss[1]+rss[2]+rss[3];
    float mu  = S * (1.0f/H_);
    float var = SS * (1.0f/H_) - mu*mu;
    stats[row*2]   = mu;
    stats[row*2+1] = rsqrtf(var + 1e-5f);
  }
}

// ======================= RoPE tables =======================
__global__ void rope_table_kernel(float* __restrict__ cost, float* __restrict__ sint)
{
  const int t = blockIdx.x;
  const int i = threadIdx.x;   // 0..31
  const float invf = (float)pow(10000.0, -(double)i / 32.0);
  const float ang  = (float)t * invf;
  cost[t*32 + i] = (float)cos((double)ang);
  sint[t*32 + i] = (float)sin((double)ang);
}

// apply RoPE in-place to q and k chunk buffers, layout [CB,T,NH,HD] flat
__global__ __launch_bounds__(256) void rope_apply_kernel(float* __restrict__ q,
    float* __restrict__ k, const float* __restrict__ cost, const float* __restrict__ sint)
{
  const int HALF = CR_*NH_*32;                 // pairs per chunk tensor
  int idx = blockIdx.x*256 + threadIdx.x;
  if(idx >= 2*HALF) return;
  float* p = (idx < HALF) ? q : k;
  int r = (idx < HALF) ? idx : idx - HALF;
  const int d  = r & 31;
  const int th = r >> 5;                       // (b*T + t)*NH + h  (b local)
  const int t  = (th >> 4) & (T_-1);           // NH=16, T=512
  const float c  = cost[t*32 + d];
  const float sn = sint[t*32 + d];
  float* pp = p + (size_t)th * HD_;
  const float x0 = pp[d];
  const float x1 = pp[d+32];
  pp[d]    = x0*c - x1*sn;
  pp[d+32] = x1*c + x0*sn;
}

// ======================= fp32 tiled GEMM =======================
// C[M,N] = op(A)[M,K] @ B[K,N] + bias
// LNA=1: A elements get (a-mu)*rstd*g[k]+b[k] applied during staging
// EPI: 0 none, 1 GELU, 2 +residual
__device__ __forceinline__ float gelu_f(float x){
  return 0.5f * x * (1.0f + erff(x * 0.7071067811865476f));
}
__device__ __forceinline__ void ln4(float4& v, float mu, float rs,
                                    const float4 g, const float4 b){
  v.x = (v.x-mu)*rs*g.x + b.x;
  v.y = (v.y-mu)*rs*g.y + b.y;
  v.z = (v.z-mu)*rs*g.z + b.z;
  v.w = (v.w-mu)*rs*g.w + b.w;
}

template<int EPI, int LNA>
__global__ __launch_bounds__(256) void gemm128(
    const float* __restrict__ A, const float* __restrict__ Bw,
    const float* __restrict__ bias, const float* __restrict__ res,
    float* __restrict__ C, int M, int N, int K,
    const float* __restrict__ stats, const float* __restrict__ lng,
    const float* __restrict__ lnb)
{
  constexpr int BM=128, BN=128, BK=16, PAD=4;
  __shared__ float As[2][BK][BM+PAD];   // transposed A tile: As[k][m]
  __shared__ float Bs[2][BK][BN+PAD];   // natural B tile:    Bs[k][n]
  const int tid = threadIdx.x;
  const int tx = tid & 15, ty = tid >> 4;
  const int bn0 = blockIdx.x * BN, bm0 = blockIdx.y * BM;

  const int ar = tid >> 1;            // A row in tile (0..127)
  const int ac = (tid & 1) * 2;       // A col4 base: cols ac*4..ac*4+7
  const int br = tid >> 4;            // B row in tile (0..15)
  const int bc = (tid & 15) * 2;      // B col4 base

  float mu = 0.f, rstd = 1.f;
  if(LNA){ mu = stats[(bm0+ar)*2]; rstd = stats[(bm0+ar)*2+1]; }

  float acc[8][8] = {};
  float4 pa[2], pb[2];
  const int KT = K / BK;

  // preload tile 0
  {
    const float* Ap = A + (size_t)(bm0 + ar)*K + ac*4;
    pa[0] = *(const float4*)Ap;  pa[1] = *(const float4*)(Ap + 4);
    if(LNA){
      const float* gp = lng + ac*4;
      const float* bp = lnb + ac*4;
      ln4(pa[0], mu, rstd, *(const float4*)gp,     *(const float4*)bp);
      ln4(pa[1], mu, rstd, *(const float4*)(gp+4), *(const float4*)(bp+4));
    }
    const float* Bp = Bw + (size_t)br*N + bn0 + bc*4;
    pb[0] = *(const float4*)Bp;  pb[1] = *(const float4*)(Bp + 4);
    #pragma unroll
    for(int u=0;u<2;u++){
      As[0][ac*4+u*4+0][ar] = ((float*)&pa[u])[0];
      As[0][ac*4+u*4+1][ar] = ((float*)&pa[u])[1];
      As[0][ac*4+u*4+2][ar] = ((float*)&pa[u])[2];
      As[0][ac*4+u*4+3][ar] = ((float*)&pa[u])[3];
    }
    *(float4*)&Bs[0][br][bc*4]   = pb[0];
    *(float4*)&Bs[0][br][bc*4+4] = pb[1];
  }
  __syncthreads();

  int buf = 0;
  for(int kt=0; kt<KT; kt++){
    if(kt+1 < KT){
      const float* Ap = A + (size_t)(bm0 + ar)*K + (kt+1)*BK + ac*4;
      pa[0] = *(const float4*)Ap;  pa[1] = *(const float4*)(Ap + 4);
      if(LNA){
        const float* gp = lng + (kt+1)*BK + ac*4;
        const float* bp = lnb + (kt+1)*BK + ac*4;
        ln4(pa[0], mu, rstd, *(const float4*)gp,     *(const float4*)bp);
        ln4(pa[1], mu, rstd, *(const float4*)(gp+4), *(const float4*)(bp+4));
      }
      const float* Bp = Bw + (size_t)((kt+1)*BK + br)*N + bn0 + bc*4;
      pb[0] = *(const float4*)Bp;  pb[1] = *(const float4*)(Bp + 4);
    }
    #pragma unroll
    for(int kk=0; kk<BK; kk++){
      float a_[8], b_[8];
      *(float4*)&a_[0] = *(const float4*)&As[buf][kk][ty*8];
      *(float4*)&a_[4] = *(const float4*)&As[buf][kk][ty*8+4];
      *(float4*)&b_[0] = *(const float4*)&Bs[buf][kk][tx*4];
      *(float4*)&b_[4] = *(const float4*)&Bs[buf][kk][64+tx*4];
      #pragma unroll
      for(int i=0;i<8;i++)
        #pragma unroll
        for(int j=0;j<8;j++)
          acc[i][j] = fmaf(a_[i], b_[j], acc[i][j]);
    }
    if(kt+1 < KT){
      #pragma unroll
      for(int u=0;u<2;u++){
        As[buf^1][ac*4+u*4+0][ar] = ((float*)&pa[u])[0];
        As[buf^1][ac*4+u*4+1][ar] = ((float*)&pa[u])[1];
        As[buf^1][ac*4+u*4+2][ar] = ((float*)&pa[u])[2];
        As[buf^1][ac*4+u*4+3][ar] = ((float*)&pa[u])[3];
      }
      *(float4*)&Bs[buf^1][br][bc*4]   = pb[0];
      *(float4*)&Bs[buf^1][br][bc*4+4] = pb[1];
    }
    __syncthreads();
    buf ^= 1;
  }

  float bv0[4], bv1[4];
  *(float4*)bv0 = *(const float4*)(bias + bn0 + tx*4);
  *(float4*)bv1 = *(const float4*)(bias + bn0 + 64 + tx*4);
  #pragma unroll
  for(int i=0;i<8;i++){
    const size_t row = bm0 + ty*8 + i;
    float o0[4], o1[4];
    #pragma unroll
    for(int j=0;j<4;j++){ o0[j] = acc[i][j] + bv0[j]; o1[j] = acc[i][4+j] + bv1[j]; }
    if(EPI==1){
      #pragma unroll
      for(int j=0;j<4;j++){ o0[j] = gelu_f(o0[j]); o1[j] = gelu_f(o1[j]); }
    }
    if(EPI==2){
      float r0[4], r1[4];
      *(float4*)r0 = *(const float4*)(res + row*N + bn0 + tx*4);
      *(float4*)r1 = *(const float4*)(res + row*N + bn0 + 64 + tx*4);
      #pragma unroll
      for(int j=0;j<4;j++){ o0[j] += r0[j]; o1[j] += r1[j]; }
    }
    *(float4*)(C + row*N + bn0 + tx*4)      = *(float4*)o0;
    *(float4*)(C + row*N + bn0 + 64 + tx*4) = *(float4*)o1;
  }
}

// ======================= Flash attention (fp32) =======================
// chunk of CB_ batches: grid (T/64, CB*NH), block 256 (16x16 threads, 4x4 each)
__global__ __launch_bounds__(256) void attn_kernel(
    const float* __restrict__ qg, const float* __restrict__ kg,
    const float* __restrict__ vg, float* __restrict__ og)
{
  __shared__ float Qt[64][68];   // Qt[d][qrow]  (transposed, pre-scaled)
  __shared__ float Kt[64][68];   // Kt[d][kcol]  (transposed)
  __shared__ float Vs[64][68];   // Vs[k][vcol]  (natural)
  __shared__ float Ps[64][68];   // Ps[qrow][k]

  const int qt = blockIdx.x;
  const int bh = blockIdx.y;
  const int b = bh >> 4, h = bh & 15;      // b local to chunk
  const int tid = threadIdx.x;
  const int tx = tid & 15, ty = tid >> 4;
  const size_t base = ((size_t)b * T_) * H_ + (size_t)h * HD_;

  const int lrow = tid >> 2;        // 0..63
  const int lpart = tid & 3;        // 0..3
  const float SCALE = 0.125f;       // 1/sqrt(64)

  #pragma unroll
  for(int j=0;j<4;j++){
    const int c = lpart*16 + j*4;
    float a_[4];
    *(float4*)a_ = *(const float4*)(qg + base + (size_t)(qt*64 + lrow)*H_ + c);
    Qt[c+0][lrow] = a_[0]*SCALE;
    Qt[c+1][lrow] = a_[1]*SCALE;
    Qt[c+2][lrow] = a_[2]*SCALE;
    Qt[c+3][lrow] = a_[3]*SCALE;
  }

  float m[4], l[4], acc[4][4];
  #pragma unroll
  for(int i=0;i<4;i++){
    m[i] = -1e30f; l[i] = 0.f;
    #pragma unroll
    for(int j=0;j<4;j++) acc[i][j] = 0.f;
  }

  for(int kt=0; kt<T_/64; kt++){
    __syncthreads();
    #pragma unroll
    for(int j=0;j<4;j++){
      const int c = lpart*16 + j*4;
      float a_[4];
      *(float4*)a_ = *(const float4*)(kg + base + (size_t)(kt*64 + lrow)*H_ + c);
      Kt[c+0][lrow] = a_[0];
      Kt[c+1][lrow] = a_[1];
      Kt[c+2][lrow] = a_[2];
      Kt[c+3][lrow] = a_[3];
      *(float4*)&Vs[lrow][c] = *(const float4*)(vg + base + (size_t)(kt*64 + lrow)*H_ + c);
    }
    __syncthreads();

    float s_[4][4] = {};
    for(int d=0; d<64; d++){
      float q_[4], k_[4];
      *(float4*)q_ = *(const float4*)&Qt[d][ty*4];
      *(float4*)k_ = *(const float4*)&Kt[d][tx*4];
      #pragma unroll
      for(int i=0;i<4;i++)
        #pragma unroll
        for(int j=0;j<4;j++)
          s_[i][j] = fmaf(q_[i], k_[j], s_[i][j]);
    }

    float tm[4], rsum[4];
    #pragma unroll
    for(int i=0;i<4;i++)
      tm[i] = fmaxf(fmaxf(s_[i][0], s_[i][1]), fmaxf(s_[i][2], s_[i][3]));
    #pragma unroll
    for(int msk=1; msk<16; msk<<=1){
      #pragma unroll
      for(int i=0;i<4;i++) tm[i] = fmaxf(tm[i], __shfl_xor(tm[i], msk));
    }
    float p_[4][4];
    #pragma unroll
    for(int i=0;i<4;i++){
      const float mn = fmaxf(m[i], tm[i]);
      const float alpha = __expf(m[i] - mn);
      m[i] = mn;
      l[i] *= alpha;
      #pragma unroll
      for(int j=0;j<4;j++) acc[i][j] *= alpha;
      float rs = 0.f;
      #pragma unroll
      for(int j=0;j<4;j++){ p_[i][j] = __expf(s_[i][j] - mn); rs += p_[i][j]; }
      rsum[i] = rs;
    }
    #pragma unroll
    for(int msk=1; msk<16; msk<<=1){
      #pragma unroll
      for(int i=0;i<4;i++) rsum[i] += __shfl_xor(rsum[i], msk);
    }
    #pragma unroll
    for(int i=0;i<4;i++) l[i] += rsum[i];
    #pragma unroll
    for(int i=0;i<4;i++) *(float4*)&Ps[ty*4+i][tx*4] = *(float4*)p_[i];
    __syncthreads();

    for(int k4=0;k4<16;k4++){
      float pr[4][4];
      #pragma unroll
      for(int i=0;i<4;i++) *(float4*)pr[i] = *(const float4*)&Ps[ty*4+i][k4*4];
      #pragma unroll
      for(int jj=0;jj<4;jj++){
        float v_[4];
        *(float4*)v_ = *(const float4*)&Vs[k4*4+jj][tx*4];
        #pragma unroll
        for(int i=0;i<4;i++)
          #pragma unroll
          for(int j=0;j<4;j++)
            acc[i][j] = fmaf(pr[i][jj], v_[j], acc[i][j]);
      }
    }
  }

  #pragma unroll
  for(int i=0;i<4;i++){
    const float inv = 1.0f / l[i];
    float o_[4];
    #pragma unroll
    for(int j=0;j<4;j++) o_[j] = acc[i][j] * inv;
    const int t = qt*64 + ty*4 + i;
    *(float4*)(og + base + (size_t)t*H_ + tx*4) = *(float4*)o_;
  }
}

// ======================= launch =======================
extern "C" void kernel_launch(void* const* d_in, const int* in_sizes, int n_in,
                              void* d_out, int out_size, void* d_ws, size_t ws_size,
                              hipStream_t stream)
{
  const float* x   = (const float*)d_in[0];
  const float* Wq  = (const float*)d_in[1];
  const float* bq  = (const float*)d_in[2];
  const float* Wk  = (const float*)d_in[3];
  const float* bk  = (const float*)d_in[4];
  const float* Wv  = (const float*)d_in[5];
  const float* bv  = (const float*)d_in[6];
  const float* Wo  = (const float*)d_in[7];
  const float* bo  = (const float*)d_in[8];
  const float* g1  = (const float*)d_in[9];
  const float* be1 = (const float*)d_in[10];
  const float* g2  = (const float*)d_in[11];
  const float* be2 = (const float*)d_in[12];
  const float* W1  = (const float*)d_in[13];
  const float* b1  = (const float*)d_in[14];
  const float* W2  = (const float*)d_in[15];
  const float* b2  = (const float*)d_in[16];
  float* out = (float*)d_out;
  float* ws  = (float*)d_ws;

  // workspace layout (floats), total 29,458,432 floats = 112.4 MB
  float* abuf = ws;                       // [BT,H] 16.7M floats — attn out; FFN h chunk aliases
  float* qc   = ws + 16777216;            // [CR,H] 4.19M
  float* kc   = ws + 20971520;            // [CR,H]
  float* vc   = ws + 25165824;            // [CR,H]
  float* st1  = ws + 29360128;            // [BT,2]
  float* st2  = st1 + 2*BT_;              // [BT,2]
  float* cost = st2 + 2*BT_;              // [T,32]
  float* sint = cost + T_*32;             // [T,32]
  float* hb   = abuf;                     // FFN h chunk [CR, FF] = 16.7M floats

  ln_stats_kernel<<<BT_, 256, 0, stream>>>(x, st1);
  rope_table_kernel<<<T_, 32, 0, stream>>>(cost, sint);

  // QKV + RoPE + attention, chunked over 4 groups of 8 batches
  for(int c=0; c<NC_; c++){
    const size_t r0 = (size_t)c * CR_;
    const float* xc = x + r0*H_;
    gemm128<0,1><<<dim3(H_/128, CR_/128), 256, 0, stream>>>(xc, Wq, bq, nullptr, qc, CR_, H_, H_, st1 + r0*2, g1, be1);
    gemm128<0,1><<<dim3(H_/128, CR_/128), 256, 0, stream>>>(xc, Wk, bk, nullptr, kc, CR_, H_, H_, st1 + r0*2, g1, be1);
    gemm128<0,1><<<dim3(H_/128, CR_/128), 256, 0, stream>>>(xc, Wv, bv, nullptr, vc, CR_, H_, H_, st1 + r0*2, g1, be1);
    rope_apply_kernel<<<(2*CR_*NH_*32)/256, 256, 0, stream>>>(qc, kc, cost, sint);
    attn_kernel<<<dim3(T_/64, CB_*NH_), 256, 0, stream>>>(qc, kc, vc, abuf + r0*H_);
  }

  // x2 = x + attn @ Wo + bo   -> d_out
  gemm128<2,0><<<dim3(H_/128, BT_/128), 256, 0, stream>>>(abuf, Wo, bo, x, out, BT_, H_, H_, nullptr, nullptr, nullptr);

  ln_stats_kernel<<<BT_, 256, 0, stream>>>(out, st2);

  // FFN in 4 row-chunks of CR_ (h chunk aliases abuf, dead after Wo GEMM)
  for(int c=0; c<NC_; c++){
    const size_t r0 = (size_t)c * CR_;
    gemm128<1,1><<<dim3(FF_/128, CR_/128), 256, 0, stream>>>(out + r0*H_, W1, b1, nullptr, hb, CR_, FF_, H_, st2 + r0*2, g2, be2);
    gemm128<2,0><<<dim3(H_/128, CR_/128), 256, 0, stream>>>(hb, W2, b2, out + r0*H_, out + r0*H_, CR_, H_, FF_, nullptr, nullptr, nullptr);
  }
}

// Round 4
// 2394.508 us; speedup vs baseline: 3.8194x; 3.8194x over previous
//
#include <hip/hip_runtime.h>
#include <math.h>

#define B_  32
#define T_  512
#define H_  1024
#define NH_ 16
#define HD_ 64
#define FF_ 4096
#define BT_ (B_*T_)   // 16384
#define CB_ 8                 // batches per chunk
#define CR_ (CB_*T_)          // rows per chunk = 4096
#define NC_ (B_/CB_)          // 4 chunks
#define MB_ (1u<<20)

typedef __attribute__((ext_vector_type(8))) short bf16x8;
typedef __attribute__((ext_vector_type(4))) short s16x4;
typedef __attribute__((ext_vector_type(4))) float f32x4;

__device__ __forceinline__ float bf2f(short h){
  unsigned u = ((unsigned)(unsigned short)h) << 16;
  return __uint_as_float(u);
}
__device__ __forceinline__ short f2bf(float f){
  unsigned u = __float_as_uint(f);
  unsigned r = (u + 0x7FFFu + ((u>>16)&1u)) >> 16;
  return (short)r;
}
__device__ __forceinline__ float gelu_f(float x){
  return 0.5f * x * (1.0f + erff(x * 0.7071067811865476f));
}

// ======================= LayerNorm stats =======================
__global__ __launch_bounds__(256) void ln_stats_kernel(const float* __restrict__ x,
    float* __restrict__ stats)
{
  const int row = blockIdx.x;
  const int tid = threadIdx.x;
  const float4 v = ((const float4*)(x + (size_t)row*H_))[tid];
  float s  = v.x+v.y+v.z+v.w;
  float ss = v.x*v.x+v.y*v.y+v.z*v.z+v.w*v.w;
  #pragma unroll
  for(int off=32; off>0; off>>=1){
    s  += __shfl_down(s, off);
    ss += __shfl_down(ss, off);
  }
  __shared__ float rs[4], rss[4];
  const int wave = tid>>6, lane = tid&63;
  if(lane==0){ rs[wave]=s; rss[wave]=ss; }
  __syncthreads();
  if(tid==0){
    float S  = rs[0]+rs[1]+rs[2]+rs[3];
    float SS = rss[0]+rss[1]+rss[2]+rss[3];
    float mu  = S * (1.0f/H_);
    float var = SS * (1.0f/H_) - mu*mu;
    stats[row*2]   = mu;
    stats[row*2+1] = rsqrtf(var + 1e-5f);
  }
}

// ======================= RoPE tables =======================
__global__ void rope_table_kernel(float* __restrict__ cost, float* __restrict__ sint)
{
  const int t = blockIdx.x;
  const int i = threadIdx.x;   // 0..31
  const float invf = (float)pow(10000.0, -(double)i / 32.0);
  const float ang  = (float)t * invf;
  cost[t*32 + i] = (float)cos((double)ang);
  sint[t*32 + i] = (float)sin((double)ang);
}

// bias concat bq|bk|bv -> bqkv[3072]
__global__ void concat3_kernel(const float* __restrict__ a, const float* __restrict__ b,
                               const float* __restrict__ c, float* __restrict__ o)
{
  int i = blockIdx.x*256 + threadIdx.x;
  if(i >= 3*H_) return;
  o[i] = (i < H_) ? a[i] : (i < 2*H_) ? b[i-H_] : c[i-2*H_];
}

// ======================= weight transpose + split =======================
// W [K][N] fp32 -> Wh [N][K] bf16 (high), Wl [N][K] bf16 (low)
__global__ __launch_bounds__(256) void tsplit_kernel(const float* __restrict__ W,
    short* __restrict__ Wh, short* __restrict__ Wl, int K, int N)
{
  __shared__ float t[32][33];
  const int n0 = blockIdx.x*32, k0 = blockIdx.y*32;
  const int tx = threadIdx.x & 31, ty = threadIdx.x >> 5;  // ty 0..7
  #pragma unroll
  for(int i=0;i<32;i+=8) t[ty+i][tx] = W[(size_t)(k0+ty+i)*N + n0+tx];  // t[k][n]
  __syncthreads();
  #pragma unroll
  for(int i=0;i<32;i+=8){
    const float f = t[tx][ty+i];           // k=k0+tx, n=n0+ty+i
    const short h = f2bf(f);
    const short l = f2bf(f - bf2f(h));
    const size_t o = (size_t)(n0+ty+i)*K + k0+tx;
    Wh[o] = h;  Wl[o] = l;
  }
}

// apply RoPE in-place to bf16 q and k chunk buffers, layout [CB,T,NH,HD]
__global__ __launch_bounds__(256) void rope_apply_kernel(short* __restrict__ q,
    short* __restrict__ k, const float* __restrict__ cost, const float* __restrict__ sint)
{
  const int HALF = CR_*NH_*32;
  int idx = blockIdx.x*256 + threadIdx.x;
  if(idx >= 2*HALF) return;
  short* p = (idx < HALF) ? q : k;
  int r = (idx < HALF) ? idx : idx - HALF;
  const int d  = r & 31;
  const int th = r >> 5;
  const int t  = (th >> 4) & (T_-1);
  const float c  = cost[t*32 + d];
  const float sn = sint[t*32 + d];
  short* pp = p + (size_t)th * HD_;
  const float x0 = bf2f(pp[d]);
  const float x1 = bf2f(pp[d+32]);
  pp[d]    = f2bf(x0*c - x1*sn);
  pp[d+32] = f2bf(x1*c + x0*sn);
}

// ======================= split-bf16 MFMA GEMM =======================
// C[M,N] = op(A)[M,K] @ W[K,N] + bias, W given as transposed split bf16 Wh/Wl [N][K]
// NTERM: 3 = Ah*Bh+Ah*Bl+Al*Bh (fp32 A), 2 = Ah*Bh+Ah*Bl (bf16 A exact)
// LNA: apply layernorm to A during staging. ASRC: 0=fp32 A, 1=bf16 A.
// EPI: 0 none, 1 GELU, 2 +res. OB: 0 fp32 C, 1 bf16 C.
// blockIdx.z selects weight/bias/C slot (QKV fusion) via zW/zC/biasZ strides.
template<int NTERM, int EPI, int LNA, int ASRC, int OB>
__global__ __launch_bounds__(256,2) void gemm_mfma(
    const void* __restrict__ Av, const short* __restrict__ Bhg,
    const short* __restrict__ Blg, const float* __restrict__ bias,
    const float* __restrict__ res, void* __restrict__ Cv,
    int M, int N, int K,
    const float* __restrict__ stats, const float* __restrict__ lng,
    const float* __restrict__ lnb,
    size_t zW, size_t zC, int biasZ)
{
  __shared__ short Ah[2][128][40];
  __shared__ short Al[(NTERM==3)?2:1][128][40];
  __shared__ short Bh[2][128][40];
  __shared__ short Bl[2][128][40];

  const int tid = threadIdx.x;
  const int z = blockIdx.z;
  const int bn0 = blockIdx.x * 128;
  const int bm0 = blockIdx.y * 128;
  const short* Bhp = Bhg + (size_t)z * zW;
  const short* Blp = Blg + (size_t)z * zW;
  const float* biasp = bias + (size_t)z * biasZ;

  const int srow  = tid >> 1;           // 0..127 (row in A/B tile)
  const int shalf = (tid & 1) * 16;     // k-half within BK=32

  float mu = 0.f, rstd = 1.f;
  if(LNA){ mu = stats[(bm0+srow)*2]; rstd = stats[(bm0+srow)*2+1]; }

  f32x4 acc[4][4];
  #pragma unroll
  for(int i=0;i<4;i++)
    #pragma unroll
    for(int j=0;j<4;j++) acc[i][j] = (f32x4){0.f,0.f,0.f,0.f};

#define STAGE(BUF, K0) do { \
    if(ASRC==0){ \
      const float* Ap = (const float*)Av + (size_t)(bm0+srow)*K + (K0) + shalf; \
      float av[16]; \
      *(float4*)&av[0]  = *(const float4*)Ap; \
      *(float4*)&av[4]  = *(const float4*)(Ap+4); \
      *(float4*)&av[8]  = *(const float4*)(Ap+8); \
      *(float4*)&av[12] = *(const float4*)(Ap+12); \
      if(LNA){ \
        const float* gp = lng + (K0)+shalf; const float* bp = lnb + (K0)+shalf; \
        for(int j=0;j<16;j++) av[j] = (av[j]-mu)*rstd*gp[j] + bp[j]; \
      } \
      short hh[16], ll[16]; \
      for(int j=0;j<16;j++){ hh[j] = f2bf(av[j]); \
        if(NTERM==3) ll[j] = f2bf(av[j] - bf2f(hh[j])); } \
      *(bf16x8*)&Ah[BUF][srow][shalf]   = *(bf16x8*)&hh[0]; \
      *(bf16x8*)&Ah[BUF][srow][shalf+8] = *(bf16x8*)&hh[8]; \
      if(NTERM==3){ \
        *(bf16x8*)&Al[BUF][srow][shalf]   = *(bf16x8*)&ll[0]; \
        *(bf16x8*)&Al[BUF][srow][shalf+8] = *(bf16x8*)&ll[8]; \
      } \
    } else { \
      const short* Ap = (const short*)Av + (size_t)(bm0+srow)*K + (K0) + shalf; \
      *(bf16x8*)&Ah[BUF][srow][shalf]   = *(const bf16x8*)Ap; \
      *(bf16x8*)&Ah[BUF][srow][shalf+8] = *(const bf16x8*)(Ap+8); \
    } \
    { const short* Bp = Bhp + (size_t)(bn0+srow)*K + (K0) + shalf; \
      *(bf16x8*)&Bh[BUF][srow][shalf]   = *(const bf16x8*)Bp; \
      *(bf16x8*)&Bh[BUF][srow][shalf+8] = *(const bf16x8*)(Bp+8); \
      const short* Bp2 = Blp + (size_t)(bn0+srow)*K + (K0) + shalf; \
      *(bf16x8*)&Bl[BUF][srow][shalf]   = *(const bf16x8*)Bp2; \
      *(bf16x8*)&Bl[BUF][srow][shalf+8] = *(const bf16x8*)(Bp2+8); \
    } \
  } while(0)

  STAGE(0, 0);
  __syncthreads();

  const int wid = tid >> 6, lane = tid & 63;
  const int wm = wid >> 1, wn = wid & 1;
  const int fr = lane & 15;        // A row-in-frag / B col-in-frag
  const int kq = lane >> 4;        // k quarter (8 elems each)

  const int KT = K / 32;
  int buf = 0;
  for(int kt=0; kt<KT; kt++){
    if(kt+1 < KT) STAGE(buf^1, (kt+1)*32);

    bf16x8 af[4], alf[4], bf[4], blf[4];
    #pragma unroll
    for(int mt=0;mt<4;mt++){
      af[mt] = *(bf16x8*)&Ah[buf][wm*64 + mt*16 + fr][kq*8];
      if(NTERM==3) alf[mt] = *(bf16x8*)&Al[buf][wm*64 + mt*16 + fr][kq*8];
    }
    #pragma unroll
    for(int nt=0;nt<4;nt++){
      bf[nt]  = *(bf16x8*)&Bh[buf][wn*64 + nt*16 + fr][kq*8];
      blf[nt] = *(bf16x8*)&Bl[buf][wn*64 + nt*16 + fr][kq*8];
    }
    #pragma unroll
    for(int mt=0;mt<4;mt++)
      #pragma unroll
      for(int nt=0;nt<4;nt++){
        acc[mt][nt] = __builtin_amdgcn_mfma_f32_16x16x32_bf16(af[mt], bf[nt],  acc[mt][nt], 0,0,0);
        acc[mt][nt] = __builtin_amdgcn_mfma_f32_16x16x32_bf16(af[mt], blf[nt], acc[mt][nt], 0,0,0);
        if(NTERM==3)
          acc[mt][nt] = __builtin_amdgcn_mfma_f32_16x16x32_bf16(alf[mt], bf[nt], acc[mt][nt], 0,0,0);
      }
    __syncthreads();
    buf ^= 1;
  }
#undef STAGE

  // epilogue: D[row][col], col = bn0+wn*64+nt*16+fr, row = bm0+wm*64+mt*16+kq*4+r
  #pragma unroll
  for(int nt=0;nt<4;nt++){
    const int col = bn0 + wn*64 + nt*16 + fr;
    const float bb = biasp[col];
    #pragma unroll
    for(int mt=0;mt<4;mt++){
      #pragma unroll
      for(int r=0;r<4;r++){
        const size_t row = bm0 + wm*64 + mt*16 + kq*4 + r;
        float v = acc[mt][nt][r] + bb;
        if(EPI==1) v = gelu_f(v);
        if(EPI==2) v += res[row*N + col];
        if(OB) ((short*)Cv)[(size_t)z*zC + row*N + col] = f2bf(v);
        else   ((float*)Cv)[(size_t)z*zC + row*N + col] = v;
      }
    }
  }
}

// ======================= Flash attention (fp32 math, bf16 IO) =======================
// chunk of CB_ batches: grid (T/64, CB*NH), block 256 (16x16 threads, 4x4 each)
__global__ __launch_bounds__(256) void attn_kernel(
    const short* __restrict__ qg, const short* __restrict__ kg,
    const short* __restrict__ vg, short* __restrict__ og)
{
  __shared__ float Qt[64][68];   // Qt[d][qrow]  (transposed, pre-scaled)
  __shared__ float Kt[64][68];   // Kt[d][kcol]
  __shared__ float Vs[64][68];   // Vs[k][vcol]
  __shared__ float Ps[64][68];   // Ps[qrow][k]

  const int qt = blockIdx.x;
  const int bh = blockIdx.y;
  const int b = bh >> 4, h = bh & 15;
  const int tid = threadIdx.x;
  const int tx = tid & 15, ty = tid >> 4;
  const size_t base = ((size_t)b * T_) * H_ + (size_t)h * HD_;

  const int lrow = tid >> 2;
  const int lpart = tid & 3;
  const float SCALE = 0.125f;

  #pragma unroll
  for(int j=0;j<4;j++){
    const int c = lpart*16 + j*4;
    const s16x4 a4 = *(const s16x4*)(qg + base + (size_t)(qt*64 + lrow)*H_ + c);
    Qt[c+0][lrow] = bf2f(a4[0])*SCALE;
    Qt[c+1][lrow] = bf2f(a4[1])*SCALE;
    Qt[c+2][lrow] = bf2f(a4[2])*SCALE;
    Qt[c+3][lrow] = bf2f(a4[3])*SCALE;
  }

  float m[4], l[4], acc[4][4];
  #pragma unroll
  for(int i=0;i<4;i++){
    m[i] = -1e30f; l[i] = 0.f;
    #pragma unroll
    for(int j=0;j<4;j++) acc[i][j] = 0.f;
  }

  for(int kt=0; kt<T_/64; kt++){
    __syncthreads();
    #pragma unroll
    for(int j=0;j<4;j++){
      const int c = lpart*16 + j*4;
      const s16x4 a4 = *(const s16x4*)(kg + base + (size_t)(kt*64 + lrow)*H_ + c);
      Kt[c+0][lrow] = bf2f(a4[0]);
      Kt[c+1][lrow] = bf2f(a4[1]);
      Kt[c+2][lrow] = bf2f(a4[2]);
      Kt[c+3][lrow] = bf2f(a4[3]);
      const s16x4 v4 = *(const s16x4*)(vg + base + (size_t)(kt*64 + lrow)*H_ + c);
      float4 vf; vf.x = bf2f(v4[0]); vf.y = bf2f(v4[1]); vf.z = bf2f(v4[2]); vf.w = bf2f(v4[3]);
      *(float4*)&Vs[lrow][c] = vf;
    }
    __syncthreads();

    float s_[4][4] = {};
    for(int d=0; d<64; d++){
      float q_[4], k_[4];
      *(float4*)q_ = *(const float4*)&Qt[d][ty*4];
      *(float4*)k_ = *(const float4*)&Kt[d][tx*4];
      #pragma unroll
      for(int i=0;i<4;i++)
        #pragma unroll
        for(int j=0;j<4;j++)
          s_[i][j] = fmaf(q_[i], k_[j], s_[i][j]);
    }

    float tm[4], rsum[4];
    #pragma unroll
    for(int i=0;i<4;i++)
      tm[i] = fmaxf(fmaxf(s_[i][0], s_[i][1]), fmaxf(s_[i][2], s_[i][3]));
    #pragma unroll
    for(int msk=1; msk<16; msk<<=1){
      #pragma unroll
      for(int i=0;i<4;i++) tm[i] = fmaxf(tm[i], __shfl_xor(tm[i], msk));
    }
    float p_[4][4];
    #pragma unroll
    for(int i=0;i<4;i++){
      const float mn = fmaxf(m[i], tm[i]);
      const float alpha = __expf(m[i] - mn);
      m[i] = mn;
      l[i] *= alpha;
      #pragma unroll
      for(int j=0;j<4;j++) acc[i][j] *= alpha;
      float rs = 0.f;
      #pragma unroll
      for(int j=0;j<4;j++){ p_[i][j] = __expf(s_[i][j] - mn); rs += p_[i][j]; }
      rsum[i] = rs;
    }
    #pragma unroll
    for(int msk=1; msk<16; msk<<=1){
      #pragma unroll
      for(int i=0;i<4;i++) rsum[i] += __shfl_xor(rsum[i], msk);
    }
    #pragma unroll
    for(int i=0;i<4;i++) l[i] += rsum[i];
    #pragma unroll
    for(int i=0;i<4;i++) *(float4*)&Ps[ty*4+i][tx*4] = *(float4*)p_[i];
    __syncthreads();

    for(int k4=0;k4<16;k4++){
      float pr[4][4];
      #pragma unroll
      for(int i=0;i<4;i++) *(float4*)pr[i] = *(const float4*)&Ps[ty*4+i][k4*4];
      #pragma unroll
      for(int jj=0;jj<4;jj++){
        float v_[4];
        *(float4*)v_ = *(const float4*)&Vs[k4*4+jj][tx*4];
        #pragma unroll
        for(int i=0;i<4;i++)
          #pragma unroll
          for(int j=0;j<4;j++)
            acc[i][j] = fmaf(pr[i][jj], v_[j], acc[i][j]);
      }
    }
  }

  #pragma unroll
  for(int i=0;i<4;i++){
    const float inv = 1.0f / l[i];
    s16x4 o4;
    #pragma unroll
    for(int j=0;j<4;j++) o4[j] = f2bf(acc[i][j] * inv);
    const int t = qt*64 + ty*4 + i;
    *(s16x4*)(og + base + (size_t)t*H_ + tx*4) = o4;
  }
}

// ======================= launch =======================
extern "C" void kernel_launch(void* const* d_in, const int* in_sizes, int n_in,
                              void* d_out, int out_size, void* d_ws, size_t ws_size,
                              hipStream_t stream)
{
  const float* x   = (const float*)d_in[0];
  const float* Wq  = (const float*)d_in[1];
  const float* bq  = (const float*)d_in[2];
  const float* Wk  = (const float*)d_in[3];
  const float* bk  = (const float*)d_in[4];
  const float* Wv  = (const float*)d_in[5];
  const float* bv  = (const float*)d_in[6];
  const float* Wo  = (const float*)d_in[7];
  const float* bo  = (const float*)d_in[8];
  const float* g1  = (const float*)d_in[9];
  const float* be1 = (const float*)d_in[10];
  const float* g2  = (const float*)d_in[11];
  const float* be2 = (const float*)d_in[12];
  const float* W1  = (const float*)d_in[13];
  const float* b1  = (const float*)d_in[14];
  const float* W2  = (const float*)d_in[15];
  const float* b2  = (const float*)d_in[16];
  float* out = (float*)d_out;
  char*  W   = (char*)d_ws;

  // ws layout (bytes), total ~104.4 MB
  short* wqkvh = (short*)(W + 0*MB_);     // [3][1024][1024] bf16
  short* wqkvl = (short*)(W + 6*MB_);
  short* woh   = (short*)(W + 12*MB_);    // [1024][1024]
  short* wol   = (short*)(W + 14*MB_);
  short* w1h   = (short*)(W + 16*MB_);    // [4096][1024]
  short* w1l   = (short*)(W + 24*MB_);
  short* w2h   = (short*)(W + 32*MB_);    // [1024][4096]
  short* w2l   = (short*)(W + 40*MB_);
  short* abuf  = (short*)(W + 48*MB_);    // [BT][H] bf16 attn-out; FFN h chunk aliases
  short* hb    = abuf;                    // [CR][FF] bf16
  short* qkvc  = (short*)(W + 80*MB_);    // [3][CR][H] bf16
  float* st1   = (float*)(W + 104*MB_);   // [BT][2]
  float* st2   = st1 + 2*BT_;
  float* cost  = st2 + 2*BT_;             // [T][32]
  float* sint  = cost + T_*32;
  float* bqkv  = sint + T_*32;            // [3][H]

  const size_t CRH = (size_t)CR_ * H_;

  ln_stats_kernel<<<BT_, 256, 0, stream>>>(x, st1);
  rope_table_kernel<<<T_, 32, 0, stream>>>(cost, sint);
  concat3_kernel<<<(3*H_+255)/256, 256, 0, stream>>>(bq, bk, bv, bqkv);

  // weight transpose+split (bf16 h/l, [N][K])
  tsplit_kernel<<<dim3(32,32),  256, 0, stream>>>(Wq, wqkvh,            wqkvl,            H_, H_);
  tsplit_kernel<<<dim3(32,32),  256, 0, stream>>>(Wk, wqkvh+1024*1024,  wqkvl+1024*1024,  H_, H_);
  tsplit_kernel<<<dim3(32,32),  256, 0, stream>>>(Wv, wqkvh+2*1024*1024,wqkvl+2*1024*1024,H_, H_);
  tsplit_kernel<<<dim3(32,32),  256, 0, stream>>>(Wo, woh, wol, H_, H_);
  tsplit_kernel<<<dim3(128,32), 256, 0, stream>>>(W1, w1h, w1l, H_, FF_);
  tsplit_kernel<<<dim3(32,128), 256, 0, stream>>>(W2, w2h, w2l, FF_, H_);

  // QKV + RoPE + attention, chunked over 4 groups of 8 batches
  for(int c=0; c<NC_; c++){
    const size_t r0 = (size_t)c * CR_;
    gemm_mfma<3,0,1,0,1><<<dim3(8, CR_/128, 3), 256, 0, stream>>>(
        x + r0*H_, wqkvh, wqkvl, bqkv, nullptr, qkvc, CR_, H_, H_,
        st1 + r0*2, g1, be1, (size_t)1024*1024, CRH, H_);
    rope_apply_kernel<<<(2*CR_*NH_*32)/256, 256, 0, stream>>>(qkvc, qkvc + CRH, cost, sint);
    attn_kernel<<<dim3(T_/64, CB_*NH_), 256, 0, stream>>>(qkvc, qkvc + CRH, qkvc + 2*CRH, abuf + r0*H_);
  }

  // x2 = x + attn @ Wo + bo   -> d_out (fp32)
  gemm_mfma<2,2,0,1,0><<<dim3(8, BT_/128, 1), 256, 0, stream>>>(
      abuf, woh, wol, bo, x, out, BT_, H_, H_, nullptr, nullptr, nullptr, 0, 0, 0);

  ln_stats_kernel<<<BT_, 256, 0, stream>>>(out, st2);

  // FFN in 4 row-chunks of CR_ (h bf16 chunk aliases abuf, dead after Wo GEMM)
  for(int c=0; c<NC_; c++){
    const size_t r0 = (size_t)c * CR_;
    gemm_mfma<3,1,1,0,1><<<dim3(FF_/128, CR_/128, 1), 256, 0, stream>>>(
        out + r0*H_, w1h, w1l, b1, nullptr, hb, CR_, FF_, H_,
        st2 + r0*2, g2, be2, 0, 0, 0);
    gemm_mfma<2,2,0,1,0><<<dim3(H_/128, CR_/128, 1), 256, 0, stream>>>(
        hb, w2h, w2l, b2, out + r0*H_, out + r0*H_, CR_, H_, FF_,
        nullptr, nullptr, nullptr, 0, 0, 0);
  }
}

// Round 5
// 1893.879 us; speedup vs baseline: 4.8290x; 1.2643x over previous
//
#include <hip/hip_runtime.h>
#include <math.h>
#include <stdint.h>

#define B_  32
#define T_  512
#define H_  1024
#define NH_ 16
#define HD_ 64
#define FF_ 4096
#define BT_ (B_*T_)   // 16384
#define CB_ 8                 // batches per chunk
#define CR_ (CB_*T_)          // rows per chunk = 4096
#define NC_ (B_/CB_)          // 4 chunks
#define MB_ ((size_t)1<<20)

typedef __attribute__((ext_vector_type(8))) short bf16x8;
typedef __attribute__((ext_vector_type(4))) short s16x4;
typedef __attribute__((ext_vector_type(4))) float f32x4;

__device__ __forceinline__ float bf2f(short h){
  unsigned u = ((unsigned)(unsigned short)h) << 16;
  return __uint_as_float(u);
}
__device__ __forceinline__ short f2bf(float f){
  unsigned u = __float_as_uint(f);
  unsigned r = (u + 0x7FFFu + ((u>>16)&1u)) >> 16;
  return (short)r;
}
__device__ __forceinline__ float gelu_f(float x){
  return 0.5f * x * (1.0f + erff(x * 0.7071067811865476f));
}

// async global->LDS, 16 bytes per lane. lds dest must be wave-uniform base;
// HW writes lane i at base + i*16.
typedef __attribute__((address_space(1))) const unsigned guint_t;
typedef __attribute__((address_space(3))) unsigned luint_t;
__device__ __forceinline__ void gld16(const void* g, void* l){
  __builtin_amdgcn_global_load_lds((guint_t*)(uintptr_t)g,
                                   (luint_t*)(unsigned)(uintptr_t)l, 16, 0, 0);
}

// ======================= fused LayerNorm -> bf16 =======================
// one block (256 thr) per row of 1024 floats; writes bf16 row
__global__ __launch_bounds__(256) void ln_bf16_kernel(const float* __restrict__ x,
    const float* __restrict__ g, const float* __restrict__ b, short* __restrict__ o)
{
  const int row = blockIdx.x;
  const int tid = threadIdx.x;
  const float4 v = ((const float4*)(x + (size_t)row*H_))[tid];
  float s  = v.x+v.y+v.z+v.w;
  float ss = v.x*v.x+v.y*v.y+v.z*v.z+v.w*v.w;
  #pragma unroll
  for(int off=32; off>0; off>>=1){
    s  += __shfl_down(s, off);
    ss += __shfl_down(ss, off);
  }
  __shared__ float rs[4], rss[4], mb[2];
  const int wave = tid>>6, lane = tid&63;
  if(lane==0){ rs[wave]=s; rss[wave]=ss; }
  __syncthreads();
  if(tid==0){
    float S  = rs[0]+rs[1]+rs[2]+rs[3];
    float SS = rss[0]+rss[1]+rss[2]+rss[3];
    float mu  = S * (1.0f/H_);
    float var = SS * (1.0f/H_) - mu*mu;
    mb[0] = mu; mb[1] = rsqrtf(var + 1e-5f);
  }
  __syncthreads();
  const float mu = mb[0], rstd = mb[1];
  const float4 gv = ((const float4*)g)[tid];
  const float4 bv = ((const float4*)b)[tid];
  s16x4 o4;
  o4[0] = f2bf((v.x-mu)*rstd*gv.x + bv.x);
  o4[1] = f2bf((v.y-mu)*rstd*gv.y + bv.y);
  o4[2] = f2bf((v.z-mu)*rstd*gv.z + bv.z);
  o4[3] = f2bf((v.w-mu)*rstd*gv.w + bv.w);
  *(s16x4*)(o + (size_t)row*H_ + tid*4) = o4;
}

// ======================= RoPE tables =======================
__global__ void rope_table_kernel(float* __restrict__ cost, float* __restrict__ sint)
{
  const int t = blockIdx.x;
  const int i = threadIdx.x;   // 0..31
  const float invf = (float)pow(10000.0, -(double)i / 32.0);
  const float ang  = (float)t * invf;
  cost[t*32 + i] = (float)cos((double)ang);
  sint[t*32 + i] = (float)sin((double)ang);
}

// bias concat bq|bk|bv -> bqkv[3072]
__global__ void concat3_kernel(const float* __restrict__ a, const float* __restrict__ b,
                               const float* __restrict__ c, float* __restrict__ o)
{
  int i = blockIdx.x*256 + threadIdx.x;
  if(i >= 3*H_) return;
  o[i] = (i < H_) ? a[i] : (i < 2*H_) ? b[i-H_] : c[i-2*H_];
}

// ======================= weight transpose + split =======================
// W [K][N] fp32 -> Wh [N][K] bf16 (high), Wl [N][K] bf16 (low)
__global__ __launch_bounds__(256) void tsplit_kernel(const float* __restrict__ W,
    short* __restrict__ Wh, short* __restrict__ Wl, int K, int N)
{
  __shared__ float t[32][33];
  const int n0 = blockIdx.x*32, k0 = blockIdx.y*32;
  const int tx = threadIdx.x & 31, ty = threadIdx.x >> 5;  // ty 0..7
  #pragma unroll
  for(int i=0;i<32;i+=8) t[ty+i][tx] = W[(size_t)(k0+ty+i)*N + n0+tx];  // t[k][n]
  __syncthreads();
  #pragma unroll
  for(int i=0;i<32;i+=8){
    const float f = t[tx][ty+i];           // k=k0+tx, n=n0+ty+i
    const short h = f2bf(f);
    const short l = f2bf(f - bf2f(h));
    const size_t o = (size_t)(n0+ty+i)*K + k0+tx;
    Wh[o] = h;  Wl[o] = l;
  }
}

// apply RoPE in-place to bf16 q and k chunk buffers, layout [CB,T,NH,HD]
__global__ __launch_bounds__(256) void rope_apply_kernel(short* __restrict__ q,
    short* __restrict__ k, const float* __restrict__ cost, const float* __restrict__ sint)
{
  const int HALF = CR_*NH_*32;
  int idx = blockIdx.x*256 + threadIdx.x;
  if(idx >= 2*HALF) return;
  short* p = (idx < HALF) ? q : k;
  int r = (idx < HALF) ? idx : idx - HALF;
  const int d  = r & 31;
  const int th = r >> 5;
  const int t  = (th >> 4) & (T_-1);
  const float c  = cost[t*32 + d];
  const float sn = sint[t*32 + d];
  short* pp = p + (size_t)th * HD_;
  const float x0 = bf2f(pp[d]);
  const float x1 = bf2f(pp[d+32]);
  pp[d]    = f2bf(x0*c - x1*sn);
  pp[d+32] = f2bf(x1*c + x0*sn);
}

// ======================= bf16 MFMA GEMM (2-term split weights) =======================
// C[M,N] = A[M,K](bf16) @ (Wh+Wl)[K,N] + bias; Wh/Wl stored [N][K] bf16.
// EPI: 0 none, 1 GELU, 2 +res(fp32). OB: 0 fp32 C, 1 bf16 C.
// blockIdx.z selects weight/bias/C slot via zW/zC/biasZ strides (QKV fusion).
template<int EPI, int OB>
__global__ __launch_bounds__(256,3) void gemm_bf2(
    const short* __restrict__ A, const short* __restrict__ Bhg,
    const short* __restrict__ Blg, const float* __restrict__ bias,
    const float* __restrict__ res, void* __restrict__ Cv,
    int M, int N, int K,
    size_t zW, size_t zC, int biasZ)
{
  __shared__ __align__(16) short Ah[2][128*32];
  __shared__ __align__(16) short Bh[2][128*32];
  __shared__ __align__(16) short Bl[2][128*32];

  const int tid = threadIdx.x;
  const int wid = tid >> 6, lane = tid & 63;
  const int z = blockIdx.z;
  const int bn0 = blockIdx.x * 128;
  const int bm0 = blockIdx.y * 128;
  const short* Bhp = Bhg + (size_t)z * zW;
  const short* Blp = Blg + (size_t)z * zW;
  const float* biasp = bias + (size_t)z * biasZ;

  // staging map: unit u = r*4+wid covers LDS shorts [u*512, u*512+512) = rows u*16..u*16+15
  // lane L: global (row = u*16 + L/4, col8 = (L&3)*8); HW writes LDS base+L*16
  const int srow0 = wid*16 + (lane>>2);
  const int scol  = (lane&3)*8;

  f32x4 acc[4][4];
  #pragma unroll
  for(int i=0;i<4;i++)
    #pragma unroll
    for(int j=0;j<4;j++) acc[i][j] = (f32x4){0.f,0.f,0.f,0.f};

#define STAGE(BUF, K0) do { \
    _Pragma("unroll") \
    for(int r=0;r<2;r++){ \
      const int rr = srow0 + r*64; \
      const int lo = (r*4+wid)*512; \
      gld16(A   + (size_t)(bm0+rr)*K + (K0) + scol, &Ah[BUF][lo]); \
      gld16(Bhp + (size_t)(bn0+rr)*K + (K0) + scol, &Bh[BUF][lo]); \
      gld16(Blp + (size_t)(bn0+rr)*K + (K0) + scol, &Bl[BUF][lo]); \
    } \
  } while(0)

  STAGE(0, 0);
  __syncthreads();

  const int wm = wid >> 1, wn = wid & 1;
  const int fr = lane & 15;        // A row-in-frag / B col-in-frag
  const int kq = lane >> 4;        // k quarter (8 elems each)

  const int KT = K / 32;
  int buf = 0;
  for(int kt=0; kt<KT; kt++){
    if(kt+1 < KT) STAGE(buf^1, (kt+1)*32);

    bf16x8 af[4], bfh[4], bfl[4];
    #pragma unroll
    for(int mt=0;mt<4;mt++)
      af[mt]  = *(bf16x8*)&Ah[buf][(wm*64 + mt*16 + fr)*32 + kq*8];
    #pragma unroll
    for(int nt=0;nt<4;nt++){
      bfh[nt] = *(bf16x8*)&Bh[buf][(wn*64 + nt*16 + fr)*32 + kq*8];
      bfl[nt] = *(bf16x8*)&Bl[buf][(wn*64 + nt*16 + fr)*32 + kq*8];
    }
    #pragma unroll
    for(int mt=0;mt<4;mt++)
      #pragma unroll
      for(int nt=0;nt<4;nt++){
        acc[mt][nt] = __builtin_amdgcn_mfma_f32_16x16x32_bf16(af[mt], bfh[nt], acc[mt][nt], 0,0,0);
        acc[mt][nt] = __builtin_amdgcn_mfma_f32_16x16x32_bf16(af[mt], bfl[nt], acc[mt][nt], 0,0,0);
      }
    __syncthreads();
    buf ^= 1;
  }
#undef STAGE

  // epilogue: col = bn0+wn*64+nt*16+fr, row = bm0+wm*64+mt*16+kq*4+r
  #pragma unroll
  for(int nt=0;nt<4;nt++){
    const int col = bn0 + wn*64 + nt*16 + fr;
    const float bb = biasp[col];
    #pragma unroll
    for(int mt=0;mt<4;mt++){
      #pragma unroll
      for(int r=0;r<4;r++){
        const size_t row = bm0 + wm*64 + mt*16 + kq*4 + r;
        float v = acc[mt][nt][r] + bb;
        if(EPI==1) v = gelu_f(v);
        if(EPI==2) v += res[row*N + col];
        if(OB) ((short*)Cv)[(size_t)z*zC + row*N + col] = f2bf(v);
        else   ((float*)Cv)[(size_t)z*zC + row*N + col] = v;
      }
    }
  }
}

// ======================= Flash attention (fp32 math, bf16 IO) =======================
__global__ __launch_bounds__(256) void attn_kernel(
    const short* __restrict__ qg, const short* __restrict__ kg,
    const short* __restrict__ vg, short* __restrict__ og)
{
  __shared__ float Qt[64][68];   // Qt[d][qrow]  (transposed, pre-scaled)
  __shared__ float Kt[64][68];   // Kt[d][kcol]
  __shared__ float Vs[64][68];   // Vs[k][vcol]
  __shared__ float Ps[64][68];   // Ps[qrow][k]

  const int qt = blockIdx.x;
  const int bh = blockIdx.y;
  const int b = bh >> 4, h = bh & 15;
  const int tid = threadIdx.x;
  const int tx = tid & 15, ty = tid >> 4;
  const size_t base = ((size_t)b * T_) * H_ + (size_t)h * HD_;

  const int lrow = tid >> 2;
  const int lpart = tid & 3;
  const float SCALE = 0.125f;

  #pragma unroll
  for(int j=0;j<4;j++){
    const int c = lpart*16 + j*4;
    const s16x4 a4 = *(const s16x4*)(qg + base + (size_t)(qt*64 + lrow)*H_ + c);
    Qt[c+0][lrow] = bf2f(a4[0])*SCALE;
    Qt[c+1][lrow] = bf2f(a4[1])*SCALE;
    Qt[c+2][lrow] = bf2f(a4[2])*SCALE;
    Qt[c+3][lrow] = bf2f(a4[3])*SCALE;
  }

  float m[4], l[4], acc[4][4];
  #pragma unroll
  for(int i=0;i<4;i++){
    m[i] = -1e30f; l[i] = 0.f;
    #pragma unroll
    for(int j=0;j<4;j++) acc[i][j] = 0.f;
  }

  for(int kt=0; kt<T_/64; kt++){
    __syncthreads();
    #pragma unroll
    for(int j=0;j<4;j++){
      const int c = lpart*16 + j*4;
      const s16x4 a4 = *(const s16x4*)(kg + base + (size_t)(kt*64 + lrow)*H_ + c);
      Kt[c+0][lrow] = bf2f(a4[0]);
      Kt[c+1][lrow] = bf2f(a4[1]);
      Kt[c+2][lrow] = bf2f(a4[2]);
      Kt[c+3][lrow] = bf2f(a4[3]);
      const s16x4 v4 = *(const s16x4*)(vg + base + (size_t)(kt*64 + lrow)*H_ + c);
      float4 vf; vf.x = bf2f(v4[0]); vf.y = bf2f(v4[1]); vf.z = bf2f(v4[2]); vf.w = bf2f(v4[3]);
      *(float4*)&Vs[lrow][c] = vf;
    }
    __syncthreads();

    float s_[4][4] = {};
    for(int d=0; d<64; d++){
      float q_[4], k_[4];
      *(float4*)q_ = *(const float4*)&Qt[d][ty*4];
      *(float4*)k_ = *(const float4*)&Kt[d][tx*4];
      #pragma unroll
      for(int i=0;i<4;i++)
        #pragma unroll
        for(int j=0;j<4;j++)
          s_[i][j] = fmaf(q_[i], k_[j], s_[i][j]);
    }

    float tm[4], rsum[4];
    #pragma unroll
    for(int i=0;i<4;i++)
      tm[i] = fmaxf(fmaxf(s_[i][0], s_[i][1]), fmaxf(s_[i][2], s_[i][3]));
    #pragma unroll
    for(int msk=1; msk<16; msk<<=1){
      #pragma unroll
      for(int i=0;i<4;i++) tm[i] = fmaxf(tm[i], __shfl_xor(tm[i], msk));
    }
    float p_[4][4];
    #pragma unroll
    for(int i=0;i<4;i++){
      const float mn = fmaxf(m[i], tm[i]);
      const float alpha = __expf(m[i] - mn);
      m[i] = mn;
      l[i] *= alpha;
      #pragma unroll
      for(int j=0;j<4;j++) acc[i][j] *= alpha;
      float rs = 0.f;
      #pragma unroll
      for(int j=0;j<4;j++){ p_[i][j] = __expf(s_[i][j] - mn); rs += p_[i][j]; }
      rsum[i] = rs;
    }
    #pragma unroll
    for(int msk=1; msk<16; msk<<=1){
      #pragma unroll
      for(int i=0;i<4;i++) rsum[i] += __shfl_xor(rsum[i], msk);
    }
    #pragma unroll
    for(int i=0;i<4;i++) l[i] += rsum[i];
    #pragma unroll
    for(int i=0;i<4;i++) *(float4*)&Ps[ty*4+i][tx*4] = *(float4*)p_[i];
    __syncthreads();

    for(int k4=0;k4<16;k4++){
      float pr[4][4];
      #pragma unroll
      for(int i=0;i<4;i++) *(float4*)pr[i] = *(const float4*)&Ps[ty*4+i][k4*4];
      #pragma unroll
      for(int jj=0;jj<4;jj++){
        float v_[4];
        *(float4*)v_ = *(const float4*)&Vs[k4*4+jj][tx*4];
        #pragma unroll
        for(int i=0;i<4;i++)
          #pragma unroll
          for(int j=0;j<4;j++)
            acc[i][j] = fmaf(pr[i][jj], v_[j], acc[i][j]);
      }
    }
  }

  #pragma unroll
  for(int i=0;i<4;i++){
    const float inv = 1.0f / l[i];
    s16x4 o4;
    #pragma unroll
    for(int j=0;j<4;j++) o4[j] = f2bf(acc[i][j] * inv);
    const int t = qt*64 + ty*4 + i;
    *(s16x4*)(og + base + (size_t)t*H_ + tx*4) = o4;
  }
}

// ======================= launch =======================
extern "C" void kernel_launch(void* const* d_in, const int* in_sizes, int n_in,
                              void* d_out, int out_size, void* d_ws, size_t ws_size,
                              hipStream_t stream)
{
  const float* x   = (const float*)d_in[0];
  const float* Wq  = (const float*)d_in[1];
  const float* bq  = (const float*)d_in[2];
  const float* Wk  = (const float*)d_in[3];
  const float* bk  = (const float*)d_in[4];
  const float* Wv  = (const float*)d_in[5];
  const float* bv  = (const float*)d_in[6];
  const float* Wo  = (const float*)d_in[7];
  const float* bo  = (const float*)d_in[8];
  const float* g1  = (const float*)d_in[9];
  const float* be1 = (const float*)d_in[10];
  const float* g2  = (const float*)d_in[11];
  const float* be2 = (const float*)d_in[12];
  const float* W1  = (const float*)d_in[13];
  const float* b1  = (const float*)d_in[14];
  const float* W2  = (const float*)d_in[15];
  const float* b2  = (const float*)d_in[16];
  float* out = (float*)d_out;
  char*  W   = (char*)d_ws;

  // ws layout (bytes), total ~112.2 MiB (proven budget: >=112.4 MiB worked in R3)
  short* wqkvh = (short*)(W + 0*MB_);     // [3][1024][1024] bf16
  short* wqkvl = (short*)(W + 6*MB_);
  short* woh   = (short*)(W + 12*MB_);    // [1024][1024]
  short* wol   = (short*)(W + 14*MB_);
  short* w1h   = (short*)(W + 16*MB_);    // [4096][1024]
  short* w1l   = (short*)(W + 24*MB_);
  short* w2h   = (short*)(W + 32*MB_);    // [1024][4096]
  short* w2l   = (short*)(W + 40*MB_);
  short* abuf  = (short*)(W + 48*MB_);    // [BT][H] bf16 attn-out; FFN h chunk aliases
  short* hb    = abuf;                    // [CR][FF] bf16
  short* qkvc  = (short*)(W + 80*MB_);    // [3][CR][H] bf16
  short* xnc   = (short*)(W + 104*MB_);   // [CR][H] bf16 LN'd activations (reused)
  float* cost  = (float*)(W + 112*MB_);   // [T][32]
  float* sint  = cost + T_*32;            // [T][32]
  float* bqkv  = sint + T_*32;            // [3][H]

  const size_t CRH = (size_t)CR_ * H_;

  rope_table_kernel<<<T_, 32, 0, stream>>>(cost, sint);
  concat3_kernel<<<(3*H_+255)/256, 256, 0, stream>>>(bq, bk, bv, bqkv);

  // weight transpose+split (bf16 h/l, [N][K])
  tsplit_kernel<<<dim3(32,32),  256, 0, stream>>>(Wq, wqkvh,            wqkvl,            H_, H_);
  tsplit_kernel<<<dim3(32,32),  256, 0, stream>>>(Wk, wqkvh+1024*1024,  wqkvl+1024*1024,  H_, H_);
  tsplit_kernel<<<dim3(32,32),  256, 0, stream>>>(Wv, wqkvh+2*1024*1024,wqkvl+2*1024*1024,H_, H_);
  tsplit_kernel<<<dim3(32,32),  256, 0, stream>>>(Wo, woh, wol, H_, H_);
  tsplit_kernel<<<dim3(128,32), 256, 0, stream>>>(W1, w1h, w1l, H_, FF_);
  tsplit_kernel<<<dim3(32,128), 256, 0, stream>>>(W2, w2h, w2l, FF_, H_);

  // QKV + RoPE + attention, chunked over 4 groups of 8 batches
  for(int c=0; c<NC_; c++){
    const size_t r0 = (size_t)c * CR_;
    ln_bf16_kernel<<<CR_, 256, 0, stream>>>(x + r0*H_, g1, be1, xnc);
    gemm_bf2<0,1><<<dim3(8, CR_/128, 3), 256, 0, stream>>>(
        xnc, wqkvh, wqkvl, bqkv, nullptr, qkvc, CR_, H_, H_,
        (size_t)1024*1024, CRH, H_);
    rope_apply_kernel<<<(2*CR_*NH_*32)/256, 256, 0, stream>>>(qkvc, qkvc + CRH, cost, sint);
    attn_kernel<<<dim3(T_/64, CB_*NH_), 256, 0, stream>>>(qkvc, qkvc + CRH, qkvc + 2*CRH, abuf + r0*H_);
  }

  // x2 = x + attn @ Wo + bo   -> d_out (fp32)
  gemm_bf2<2,0><<<dim3(8, BT_/128, 1), 256, 0, stream>>>(
      abuf, woh, wol, bo, x, out, BT_, H_, H_, 0, 0, 0);

  // FFN in 4 row-chunks of CR_ (h bf16 chunk aliases abuf, dead after Wo GEMM)
  for(int c=0; c<NC_; c++){
    const size_t r0 = (size_t)c * CR_;
    ln_bf16_kernel<<<CR_, 256, 0, stream>>>(out + r0*H_, g2, be2, xnc);
    gemm_bf2<1,1><<<dim3(FF_/128, CR_/128, 1), 256, 0, stream>>>(
        xnc, w1h, w1l, b1, nullptr, hb, CR_, FF_, H_, 0, 0, 0);
    gemm_bf2<2,0><<<dim3(H_/128, CR_/128, 1), 256, 0, stream>>>(
        hb, w2h, w2l, b2, out + r0*H_, out + r0*H_, CR_, H_, FF_, 0, 0, 0);
  }
}

// Round 6
// 1417.587 us; speedup vs baseline: 6.4515x; 1.3360x over previous
//
#include <hip/hip_runtime.h>
#include <math.h>
#include <stdint.h>

#define B_  32
#define T_  512
#define H_  1024
#define NH_ 16
#define HD_ 64
#define FF_ 4096
#define BT_ (B_*T_)   // 16384
#define CB_ 8                 // batches per chunk
#define CR_ (CB_*T_)          // rows per chunk = 4096
#define NC_ (B_/CB_)          // 4 chunks
#define MB_ ((size_t)1<<20)

typedef __attribute__((ext_vector_type(8))) short bf16x8;
typedef __attribute__((ext_vector_type(4))) short s16x4;
typedef __attribute__((ext_vector_type(4))) float f32x4;

__device__ __forceinline__ float bf2f(short h){
  unsigned u = ((unsigned)(unsigned short)h) << 16;
  return __uint_as_float(u);
}
__device__ __forceinline__ short f2bf(float f){
  unsigned u = __float_as_uint(f);
  unsigned r = (u + 0x7FFFu + ((u>>16)&1u)) >> 16;
  return (short)r;
}
__device__ __forceinline__ float gelu_f(float x){
  return 0.5f * x * (1.0f + erff(x * 0.7071067811865476f));
}

// async global->LDS, 16 bytes per lane; lds dest wave-uniform base, HW writes lane i at base+i*16
typedef __attribute__((address_space(1))) const unsigned guint_t;
typedef __attribute__((address_space(3))) unsigned luint_t;
__device__ __forceinline__ void gld16(const void* g, void* l){
  __builtin_amdgcn_global_load_lds((guint_t*)(uintptr_t)g,
                                   (luint_t*)(unsigned)(uintptr_t)l, 16, 0, 0);
}

// ======================= fused LayerNorm -> bf16 =======================
__global__ __launch_bounds__(256) void ln_bf16_kernel(const float* __restrict__ x,
    const float* __restrict__ g, const float* __restrict__ b, short* __restrict__ o)
{
  const int row = blockIdx.x;
  const int tid = threadIdx.x;
  const float4 v = ((const float4*)(x + (size_t)row*H_))[tid];
  float s  = v.x+v.y+v.z+v.w;
  float ss = v.x*v.x+v.y*v.y+v.z*v.z+v.w*v.w;
  #pragma unroll
  for(int off=32; off>0; off>>=1){
    s  += __shfl_down(s, off);
    ss += __shfl_down(ss, off);
  }
  __shared__ float rs[4], rss[4], mb[2];
  const int wave = tid>>6, lane = tid&63;
  if(lane==0){ rs[wave]=s; rss[wave]=ss; }
  __syncthreads();
  if(tid==0){
    float S  = rs[0]+rs[1]+rs[2]+rs[3];
    float SS = rss[0]+rss[1]+rss[2]+rss[3];
    float mu  = S * (1.0f/H_);
    float var = SS * (1.0f/H_) - mu*mu;
    mb[0] = mu; mb[1] = rsqrtf(var + 1e-5f);
  }
  __syncthreads();
  const float mu = mb[0], rstd = mb[1];
  const float4 gv = ((const float4*)g)[tid];
  const float4 bv = ((const float4*)b)[tid];
  s16x4 o4;
  o4[0] = f2bf((v.x-mu)*rstd*gv.x + bv.x);
  o4[1] = f2bf((v.y-mu)*rstd*gv.y + bv.y);
  o4[2] = f2bf((v.z-mu)*rstd*gv.z + bv.z);
  o4[3] = f2bf((v.w-mu)*rstd*gv.w + bv.w);
  *(s16x4*)(o + (size_t)row*H_ + tid*4) = o4;
}

// ======================= RoPE tables =======================
__global__ void rope_table_kernel(float* __restrict__ cost, float* __restrict__ sint)
{
  const int t = blockIdx.x;
  const int i = threadIdx.x;   // 0..31
  const float invf = (float)pow(10000.0, -(double)i / 32.0);
  const float ang  = (float)t * invf;
  cost[t*32 + i] = (float)cos((double)ang);
  sint[t*32 + i] = (float)sin((double)ang);
}

// bias concat bq|bk|bv -> bqkv[3072]
__global__ void concat3_kernel(const float* __restrict__ a, const float* __restrict__ b,
                               const float* __restrict__ c, float* __restrict__ o)
{
  int i = blockIdx.x*256 + threadIdx.x;
  if(i >= 3*H_) return;
  o[i] = (i < H_) ? a[i] : (i < 2*H_) ? b[i-H_] : c[i-2*H_];
}

// ======================= weight transpose + split =======================
__global__ __launch_bounds__(256) void tsplit_kernel(const float* __restrict__ W,
    short* __restrict__ Wh, short* __restrict__ Wl, int K, int N)
{
  __shared__ float t[32][33];
  const int n0 = blockIdx.x*32, k0 = blockIdx.y*32;
  const int tx = threadIdx.x & 31, ty = threadIdx.x >> 5;  // ty 0..7
  #pragma unroll
  for(int i=0;i<32;i+=8) t[ty+i][tx] = W[(size_t)(k0+ty+i)*N + n0+tx];
  __syncthreads();
  #pragma unroll
  for(int i=0;i<32;i+=8){
    const float f = t[tx][ty+i];           // k=k0+tx, n=n0+ty+i
    const short h = f2bf(f);
    const short l = f2bf(f - bf2f(h));
    const size_t o = (size_t)(n0+ty+i)*K + k0+tx;
    Wh[o] = h;  Wl[o] = l;
  }
}

// ======================= bf16 MFMA GEMM (2-term split weights) =======================
template<int EPI, int OB>
__global__ __launch_bounds__(256,3) void gemm_bf2(
    const short* __restrict__ A, const short* __restrict__ Bhg,
    const short* __restrict__ Blg, const float* __restrict__ bias,
    const float* __restrict__ res, void* __restrict__ Cv,
    int M, int N, int K,
    size_t zW, size_t zC, int biasZ)
{
  __shared__ __align__(16) short Ah[2][128*32];
  __shared__ __align__(16) short Bh[2][128*32];
  __shared__ __align__(16) short Bl[2][128*32];

  const int tid = threadIdx.x;
  const int wid = tid >> 6, lane = tid & 63;
  const int z = blockIdx.z;
  const int bn0 = blockIdx.x * 128;
  const int bm0 = blockIdx.y * 128;
  const short* Bhp = Bhg + (size_t)z * zW;
  const short* Blp = Blg + (size_t)z * zW;
  const float* biasp = bias + (size_t)z * biasZ;

  const int srow0 = wid*16 + (lane>>2);
  const int scol  = (lane&3)*8;

  f32x4 acc[4][4];
  #pragma unroll
  for(int i=0;i<4;i++)
    #pragma unroll
    for(int j=0;j<4;j++) acc[i][j] = (f32x4){0.f,0.f,0.f,0.f};

#define STAGE(BUF, K0) do { \
    _Pragma("unroll") \
    for(int r=0;r<2;r++){ \
      const int rr = srow0 + r*64; \
      const int lo = (r*4+wid)*512; \
      gld16(A   + (size_t)(bm0+rr)*K + (K0) + scol, &Ah[BUF][lo]); \
      gld16(Bhp + (size_t)(bn0+rr)*K + (K0) + scol, &Bh[BUF][lo]); \
      gld16(Blp + (size_t)(bn0+rr)*K + (K0) + scol, &Bl[BUF][lo]); \
    } \
  } while(0)

  STAGE(0, 0);
  __syncthreads();

  const int wm = wid >> 1, wn = wid & 1;
  const int fr = lane & 15;
  const int kq = lane >> 4;

  const int KT = K / 32;
  int buf = 0;
  for(int kt=0; kt<KT; kt++){
    if(kt+1 < KT) STAGE(buf^1, (kt+1)*32);

    bf16x8 af[4], bfh[4], bfl[4];
    #pragma unroll
    for(int mt=0;mt<4;mt++)
      af[mt]  = *(bf16x8*)&Ah[buf][(wm*64 + mt*16 + fr)*32 + kq*8];
    #pragma unroll
    for(int nt=0;nt<4;nt++){
      bfh[nt] = *(bf16x8*)&Bh[buf][(wn*64 + nt*16 + fr)*32 + kq*8];
      bfl[nt] = *(bf16x8*)&Bl[buf][(wn*64 + nt*16 + fr)*32 + kq*8];
    }
    #pragma unroll
    for(int mt=0;mt<4;mt++)
      #pragma unroll
      for(int nt=0;nt<4;nt++){
        acc[mt][nt] = __builtin_amdgcn_mfma_f32_16x16x32_bf16(af[mt], bfh[nt], acc[mt][nt], 0,0,0);
        acc[mt][nt] = __builtin_amdgcn_mfma_f32_16x16x32_bf16(af[mt], bfl[nt], acc[mt][nt], 0,0,0);
      }
    __syncthreads();
    buf ^= 1;
  }
#undef STAGE

  #pragma unroll
  for(int nt=0;nt<4;nt++){
    const int col = bn0 + wn*64 + nt*16 + fr;
    const float bb = biasp[col];
    #pragma unroll
    for(int mt=0;mt<4;mt++){
      #pragma unroll
      for(int r=0;r<4;r++){
        const size_t row = bm0 + wm*64 + mt*16 + kq*4 + r;
        float v = acc[mt][nt][r] + bb;
        if(EPI==1) v = gelu_f(v);
        if(EPI==2) v += res[row*N + col];
        if(OB) ((short*)Cv)[(size_t)z*zC + row*N + col] = f2bf(v);
        else   ((float*)Cv)[(size_t)z*zC + row*N + col] = v;
      }
    }
  }
}

// ======================= MFMA flash attention (bf16, rope fused in staging) =======================
// grid (T/64, CB*NH), 256 thr = 4 waves; wave w owns q rows w*16..w*16+15 of the 64-row Q tile.
// Swapped QK^T: S^T = mfma(K, Q) so softmax state is lane-scalar (q = lane&15).
__global__ __launch_bounds__(256,4) void attn_mfma_kernel(
    const short* __restrict__ qg, const short* __restrict__ kg,
    const short* __restrict__ vg, short* __restrict__ og,
    const float* __restrict__ cost, const float* __restrict__ sint)
{
  __shared__ __align__(16) short Q_lds[64][72];
  __shared__ __align__(16) short K_lds[64][72];
  __shared__ __align__(16) short Vt[64][72];    // Vt[d][k]
  __shared__ __align__(16) short P_lds[64][72]; // P[q][k]

  const int qt = blockIdx.x;
  const int bh = blockIdx.y;
  const int b = bh >> 4, h = bh & 15;
  const int tid = threadIdx.x;
  const int wid = tid >> 6, lane = tid & 63;
  const size_t base = ((size_t)b*T_)*H_ + (size_t)h*HD_;

  const int srow = tid >> 2;        // 0..63
  const int sc8  = (tid & 3) * 8;   // 0,8,16,24 (first-half d)
  const int sc16 = (tid & 3) * 16;  // V staging col base

  // --- stage Q with rope + 1/sqrt(64) scale ---
  {
    const int t = qt*64 + srow;
    const short* qp = qg + base + (size_t)t*H_;
    bf16x8 lo = *(const bf16x8*)(qp + sc8);
    bf16x8 hi = *(const bf16x8*)(qp + sc8 + 32);
    float cc[8], ss[8];
    *(float4*)&cc[0] = *(const float4*)(cost + t*32 + sc8);
    *(float4*)&cc[4] = *(const float4*)(cost + t*32 + sc8 + 4);
    *(float4*)&ss[0] = *(const float4*)(sint + t*32 + sc8);
    *(float4*)&ss[4] = *(const float4*)(sint + t*32 + sc8 + 4);
    short olo[8], ohi[8];
    #pragma unroll
    for(int j=0;j<8;j++){
      const float x0 = bf2f(lo[j]), x1 = bf2f(hi[j]);
      olo[j] = f2bf((x0*cc[j] - x1*ss[j])*0.125f);
      ohi[j] = f2bf((x1*cc[j] + x0*ss[j])*0.125f);
    }
    *(bf16x8*)&Q_lds[srow][sc8]    = *(bf16x8*)olo;
    *(bf16x8*)&Q_lds[srow][sc8+32] = *(bf16x8*)ohi;
  }

  const int fr = lane & 15;   // this lane's q slot (within wave tile) / frag col
  const int g  = lane >> 4;   // lane group
  const int wq0 = wid * 16;

  float m_run = -1e30f, l_run = 0.f;
  f32x4 acc[4];
  #pragma unroll
  for(int i=0;i<4;i++) acc[i] = (f32x4){0.f,0.f,0.f,0.f};

  for(int kt=0; kt<T_/64; kt++){
    __syncthreads();   // all waves done reading K/Vt (first iter: Q staged)
    // --- stage K (rope) + V (transposed) ---
    {
      const int t = kt*64 + srow;
      const short* kp = kg + base + (size_t)t*H_;
      bf16x8 lo = *(const bf16x8*)(kp + sc8);
      bf16x8 hi = *(const bf16x8*)(kp + sc8 + 32);
      float cc[8], ss[8];
      *(float4*)&cc[0] = *(const float4*)(cost + t*32 + sc8);
      *(float4*)&cc[4] = *(const float4*)(cost + t*32 + sc8 + 4);
      *(float4*)&ss[0] = *(const float4*)(sint + t*32 + sc8);
      *(float4*)&ss[4] = *(const float4*)(sint + t*32 + sc8 + 4);
      short olo[8], ohi[8];
      #pragma unroll
      for(int j=0;j<8;j++){
        const float x0 = bf2f(lo[j]), x1 = bf2f(hi[j]);
        olo[j] = f2bf(x0*cc[j] - x1*ss[j]);
        ohi[j] = f2bf(x1*cc[j] + x0*ss[j]);
      }
      *(bf16x8*)&K_lds[srow][sc8]    = *(bf16x8*)olo;
      *(bf16x8*)&K_lds[srow][sc8+32] = *(bf16x8*)ohi;

      const short* vp = vg + base + (size_t)t*H_;
      bf16x8 v0 = *(const bf16x8*)(vp + sc16);
      bf16x8 v1 = *(const bf16x8*)(vp + sc16 + 8);
      #pragma unroll
      for(int j=0;j<8;j++){
        Vt[sc16+j][srow]   = v0[j];
        Vt[sc16+8+j][srow] = v1[j];
      }
    }
    __syncthreads();

    // --- S^T frags: sfr[mt] covers k rows mt*16..+15 for this wave's 16 q cols ---
    f32x4 sfr[4];
    #pragma unroll
    for(int mt=0;mt<4;mt++) sfr[mt] = (f32x4){0.f,0.f,0.f,0.f};
    #pragma unroll
    for(int kk=0;kk<2;kk++){
      const bf16x8 qf = *(bf16x8*)&Q_lds[wq0 + fr][kk*32 + g*8];
      #pragma unroll
      for(int mt=0;mt<4;mt++){
        const bf16x8 kf = *(bf16x8*)&K_lds[mt*16 + fr][kk*32 + g*8];
        sfr[mt] = __builtin_amdgcn_mfma_f32_16x16x32_bf16(kf, qf, sfr[mt], 0,0,0);
      }
    }

    // --- online softmax (state per lane; q = wq0+fr) ---
    float tmax = -1e30f;
    #pragma unroll
    for(int mt=0;mt<4;mt++)
      #pragma unroll
      for(int r=0;r<4;r++) tmax = fmaxf(tmax, sfr[mt][r]);
    tmax = fmaxf(tmax, __shfl_xor(tmax, 16));
    tmax = fmaxf(tmax, __shfl_xor(tmax, 32));
    const float mn = fmaxf(m_run, tmax);
    const float alpha = __expf(m_run - mn);
    m_run = mn;
    float psum = 0.f;
    short pb[4][4];
    #pragma unroll
    for(int mt=0;mt<4;mt++)
      #pragma unroll
      for(int r=0;r<4;r++){
        const short pbf = f2bf(__expf(sfr[mt][r] - mn));
        pb[mt][r] = pbf;
        psum += bf2f(pbf);
      }
    psum += __shfl_xor(psum, 16);
    psum += __shfl_xor(psum, 32);
    l_run = l_run*alpha + psum;

    // write P rows (own wave rows only; same-wave LDS RAW ordered by compiler)
    #pragma unroll
    for(int mt=0;mt<4;mt++)
      *(s16x4*)&P_lds[wq0 + fr][mt*16 + g*4] = *(s16x4*)pb[mt];

    // rescale O acc by per-row alpha (acc rows are q = wq0 + 4g + r)
    float a_r[4];
    #pragma unroll
    for(int r=0;r<4;r++) a_r[r] = __shfl(alpha, (lane & 48) | (4*g + r));
    #pragma unroll
    for(int nt=0;nt<4;nt++)
      #pragma unroll
      for(int r=0;r<4;r++) acc[nt][r] *= a_r[r];

    // --- PV: acc[nt] += P[q][k] @ V[k][d] ---
    #pragma unroll
    for(int kk=0;kk<2;kk++){
      const bf16x8 pf = *(bf16x8*)&P_lds[wq0 + fr][kk*32 + g*8];
      #pragma unroll
      for(int nt=0;nt<4;nt++){
        const bf16x8 vf = *(bf16x8*)&Vt[nt*16 + fr][kk*32 + g*8];
        acc[nt] = __builtin_amdgcn_mfma_f32_16x16x32_bf16(pf, vf, acc[nt], 0,0,0);
      }
    }
  }

  // --- epilogue: O row q = wq0+4g+r, col d = nt*16+fr ---
  float linv[4];
  #pragma unroll
  for(int r=0;r<4;r++) linv[r] = 1.0f / __shfl(l_run, (lane & 48) | (4*g + r));
  #pragma unroll
  for(int nt=0;nt<4;nt++){
    const int d = nt*16 + fr;
    #pragma unroll
    for(int r=0;r<4;r++){
      const int t = qt*64 + wq0 + 4*g + r;
      og[base + (size_t)t*H_ + d] = f2bf(acc[nt][r] * linv[r]);
    }
  }
}

// ======================= launch =======================
extern "C" void kernel_launch(void* const* d_in, const int* in_sizes, int n_in,
                              void* d_out, int out_size, void* d_ws, size_t ws_size,
                              hipStream_t stream)
{
  const float* x   = (const float*)d_in[0];
  const float* Wq  = (const float*)d_in[1];
  const float* bq  = (const float*)d_in[2];
  const float* Wk  = (const float*)d_in[3];
  const float* bk  = (const float*)d_in[4];
  const float* Wv  = (const float*)d_in[5];
  const float* bv  = (const float*)d_in[6];
  const float* Wo  = (const float*)d_in[7];
  const float* bo  = (const float*)d_in[8];
  const float* g1  = (const float*)d_in[9];
  const float* be1 = (const float*)d_in[10];
  const float* g2  = (const float*)d_in[11];
  const float* be2 = (const float*)d_in[12];
  const float* W1  = (const float*)d_in[13];
  const float* b1  = (const float*)d_in[14];
  const float* W2  = (const float*)d_in[15];
  const float* b2  = (const float*)d_in[16];
  float* out = (float*)d_out;
  char*  W   = (char*)d_ws;

  // ws layout (bytes), total ~112.2 MiB (proven budget)
  short* wqkvh = (short*)(W + 0*MB_);     // [3][1024][1024] bf16
  short* wqkvl = (short*)(W + 6*MB_);
  short* woh   = (short*)(W + 12*MB_);    // [1024][1024]
  short* wol   = (short*)(W + 14*MB_);
  short* w1h   = (short*)(W + 16*MB_);    // [4096][1024]
  short* w1l   = (short*)(W + 24*MB_);
  short* w2h   = (short*)(W + 32*MB_);    // [1024][4096]
  short* w2l   = (short*)(W + 40*MB_);
  short* abuf  = (short*)(W + 48*MB_);    // [BT][H] bf16 attn-out; FFN h chunk aliases
  short* hb    = abuf;                    // [CR][FF] bf16
  short* qkvc  = (short*)(W + 80*MB_);    // [3][CR][H] bf16
  short* xnc   = (short*)(W + 104*MB_);   // [CR][H] bf16 LN'd activations (reused)
  float* cost  = (float*)(W + 112*MB_);   // [T][32]
  float* sint  = cost + T_*32;            // [T][32]
  float* bqkv  = sint + T_*32;            // [3][H]

  const size_t CRH = (size_t)CR_ * H_;

  rope_table_kernel<<<T_, 32, 0, stream>>>(cost, sint);
  concat3_kernel<<<(3*H_+255)/256, 256, 0, stream>>>(bq, bk, bv, bqkv);

  // weight transpose+split (bf16 h/l, [N][K])
  tsplit_kernel<<<dim3(32,32),  256, 0, stream>>>(Wq, wqkvh,            wqkvl,            H_, H_);
  tsplit_kernel<<<dim3(32,32),  256, 0, stream>>>(Wk, wqkvh+1024*1024,  wqkvl+1024*1024,  H_, H_);
  tsplit_kernel<<<dim3(32,32),  256, 0, stream>>>(Wv, wqkvh+2*1024*1024,wqkvl+2*1024*1024,H_, H_);
  tsplit_kernel<<<dim3(32,32),  256, 0, stream>>>(Wo, woh, wol, H_, H_);
  tsplit_kernel<<<dim3(128,32), 256, 0, stream>>>(W1, w1h, w1l, H_, FF_);
  tsplit_kernel<<<dim3(32,128), 256, 0, stream>>>(W2, w2h, w2l, FF_, H_);

  // QKV + attention (rope fused in attn staging), chunked over 4 groups of 8 batches
  for(int c=0; c<NC_; c++){
    const size_t r0 = (size_t)c * CR_;
    ln_bf16_kernel<<<CR_, 256, 0, stream>>>(x + r0*H_, g1, be1, xnc);
    gemm_bf2<0,1><<<dim3(8, CR_/128, 3), 256, 0, stream>>>(
        xnc, wqkvh, wqkvl, bqkv, nullptr, qkvc, CR_, H_, H_,
        (size_t)1024*1024, CRH, H_);
    attn_mfma_kernel<<<dim3(T_/64, CB_*NH_), 256, 0, stream>>>(
        qkvc, qkvc + CRH, qkvc + 2*CRH, abuf + r0*H_, cost, sint);
  }

  // x2 = x + attn @ Wo + bo   -> d_out (fp32)
  gemm_bf2<2,0><<<dim3(8, BT_/128, 1), 256, 0, stream>>>(
      abuf, woh, wol, bo, x, out, BT_, H_, H_, 0, 0, 0);

  // FFN in 4 row-chunks of CR_ (h bf16 chunk aliases abuf, dead after Wo GEMM)
  for(int c=0; c<NC_; c++){
    const size_t r0 = (size_t)c * CR_;
    ln_bf16_kernel<<<CR_, 256, 0, stream>>>(out + r0*H_, g2, be2, xnc);
    gemm_bf2<1,1><<<dim3(FF_/128, CR_/128, 1), 256, 0, stream>>>(
        xnc, w1h, w1l, b1, nullptr, hb, CR_, FF_, H_, 0, 0, 0);
    gemm_bf2<2,0><<<dim3(H_/128, CR_/128, 1), 256, 0, stream>>>(
        hb, w2h, w2l, b2, out + r0*H_, out + r0*H_, CR_, H_, FF_, 0, 0, 0);
  }
}

// Round 7
// 1156.554 us; speedup vs baseline: 7.9076x; 1.2257x over previous
//
#include <hip/hip_runtime.h>
#include <math.h>
#include <stdint.h>

#define B_  32
#define T_  512
#define H_  1024
#define NH_ 16
#define HD_ 64
#define FF_ 4096
#define BT_ (B_*T_)   // 16384
#define CB_ 8                 // batches per chunk
#define CR_ (CB_*T_)          // rows per chunk = 4096
#define NC_ (B_/CB_)          // 4 chunks
#define MB_ ((size_t)1<<20)

typedef _Float16 h16;
typedef __attribute__((ext_vector_type(8))) _Float16 f16x8;
typedef __attribute__((ext_vector_type(4))) _Float16 f16x4;
typedef __attribute__((ext_vector_type(4))) float f32x4;

__device__ __forceinline__ float gelu_f(float x){
  return 0.5f * x * (1.0f + erff(x * 0.7071067811865476f));
}

// async global->LDS, 16 bytes per lane; lds dest wave-uniform base, HW writes lane i at base+i*16
typedef __attribute__((address_space(1))) const unsigned guint_t;
typedef __attribute__((address_space(3))) unsigned luint_t;
__device__ __forceinline__ void gld16(const void* g, void* l){
  __builtin_amdgcn_global_load_lds((guint_t*)(uintptr_t)g,
                                   (luint_t*)(unsigned)(uintptr_t)l, 16, 0, 0);
}

// ======================= fused LayerNorm -> f16 =======================
__global__ __launch_bounds__(256) void ln_f16_kernel(const float* __restrict__ x,
    const float* __restrict__ g, const float* __restrict__ b, h16* __restrict__ o)
{
  const int row = blockIdx.x;
  const int tid = threadIdx.x;
  const float4 v = ((const float4*)(x + (size_t)row*H_))[tid];
  float s  = v.x+v.y+v.z+v.w;
  float ss = v.x*v.x+v.y*v.y+v.z*v.z+v.w*v.w;
  #pragma unroll
  for(int off=32; off>0; off>>=1){
    s  += __shfl_down(s, off);
    ss += __shfl_down(ss, off);
  }
  __shared__ float rs[4], rss[4], mb[2];
  const int wave = tid>>6, lane = tid&63;
  if(lane==0){ rs[wave]=s; rss[wave]=ss; }
  __syncthreads();
  if(tid==0){
    float S  = rs[0]+rs[1]+rs[2]+rs[3];
    float SS = rss[0]+rss[1]+rss[2]+rss[3];
    float mu  = S * (1.0f/H_);
    float var = SS * (1.0f/H_) - mu*mu;
    mb[0] = mu; mb[1] = rsqrtf(var + 1e-5f);
  }
  __syncthreads();
  const float mu = mb[0], rstd = mb[1];
  const float4 gv = ((const float4*)g)[tid];
  const float4 bv = ((const float4*)b)[tid];
  f16x4 o4;
  o4[0] = (h16)((v.x-mu)*rstd*gv.x + bv.x);
  o4[1] = (h16)((v.y-mu)*rstd*gv.y + bv.y);
  o4[2] = (h16)((v.z-mu)*rstd*gv.z + bv.z);
  o4[3] = (h16)((v.w-mu)*rstd*gv.w + bv.w);
  *(f16x4*)(o + (size_t)row*H_ + tid*4) = o4;
}

// ======================= RoPE tables =======================
__global__ void rope_table_kernel(float* __restrict__ cost, float* __restrict__ sint)
{
  const int t = blockIdx.x;
  const int i = threadIdx.x;   // 0..31
  const float invf = (float)pow(10000.0, -(double)i / 32.0);
  const float ang  = (float)t * invf;
  cost[t*32 + i] = (float)cos((double)ang);
  sint[t*32 + i] = (float)sin((double)ang);
}

// bias concat bq|bk|bv -> bqkv[3072]
__global__ void concat3_kernel(const float* __restrict__ a, const float* __restrict__ b,
                               const float* __restrict__ c, float* __restrict__ o)
{
  int i = blockIdx.x*256 + threadIdx.x;
  if(i >= 3*H_) return;
  o[i] = (i < H_) ? a[i] : (i < 2*H_) ? b[i-H_] : c[i-2*H_];
}

// ======================= weight transpose + convert =======================
// W [K][N] fp32 -> Wt [N][K] f16
__global__ __launch_bounds__(256) void tcvt_kernel(const float* __restrict__ W,
    h16* __restrict__ Wt, int K, int N)
{
  __shared__ float t[32][33];
  const int n0 = blockIdx.x*32, k0 = blockIdx.y*32;
  const int tx = threadIdx.x & 31, ty = threadIdx.x >> 5;  // ty 0..7
  #pragma unroll
  for(int i=0;i<32;i+=8) t[ty+i][tx] = W[(size_t)(k0+ty+i)*N + n0+tx];
  __syncthreads();
  #pragma unroll
  for(int i=0;i<32;i+=8){
    const float f = t[tx][ty+i];           // k=k0+tx, n=n0+ty+i
    Wt[(size_t)(n0+ty+i)*K + k0+tx] = (h16)f;
  }
}

// ======================= f16 MFMA GEMM =======================
// C[M,N] = A[M,K](f16) @ W[K,N] + bias; W stored [N][K] f16.
// EPI: 0 none, 1 GELU, 2 +res(fp32). OB: 0 fp32 C, 1 f16 C.
// blockIdx.z selects weight/bias/C slot via zW/zC/biasZ strides (QKV fusion).
template<int EPI, int OB>
__global__ __launch_bounds__(256,4) void gemm_f16(
    const h16* __restrict__ A, const h16* __restrict__ Bg,
    const float* __restrict__ bias, const float* __restrict__ res,
    void* __restrict__ Cv, int M, int N, int K,
    size_t zW, size_t zC, int biasZ)
{
  __shared__ __align__(16) h16 Ah[2][128*32];
  __shared__ __align__(16) h16 Bh[2][128*32];

  const int tid = threadIdx.x;
  const int wid = tid >> 6, lane = tid & 63;
  const int z = blockIdx.z;
  const int bn0 = blockIdx.x * 128;
  const int bm0 = blockIdx.y * 128;
  const h16* Bp = Bg + (size_t)z * zW;
  const float* biasp = bias + (size_t)z * biasZ;

  // staging map: unit u = r*4+wid covers LDS elems [u*512, u*512+512) = rows u*16..u*16+15
  // lane L: global (row = u*16 + L/4, col8 = (L&3)*8); HW writes LDS base+L*16
  const int srow0 = wid*16 + (lane>>2);
  const int scol  = (lane&3)*8;

  f32x4 acc[4][4];
  #pragma unroll
  for(int i=0;i<4;i++)
    #pragma unroll
    for(int j=0;j<4;j++) acc[i][j] = (f32x4){0.f,0.f,0.f,0.f};

#define STAGE(BUF, K0) do { \
    _Pragma("unroll") \
    for(int r=0;r<2;r++){ \
      const int rr = srow0 + r*64; \
      const int lo = (r*4+wid)*512; \
      gld16(A  + (size_t)(bm0+rr)*K + (K0) + scol, &Ah[BUF][lo]); \
      gld16(Bp + (size_t)(bn0+rr)*K + (K0) + scol, &Bh[BUF][lo]); \
    } \
  } while(0)

  STAGE(0, 0);
  __syncthreads();

  const int wm = wid >> 1, wn = wid & 1;
  const int fr = lane & 15;
  const int kq = lane >> 4;

  const int KT = K / 32;
  int buf = 0;
  for(int kt=0; kt<KT; kt++){
    if(kt+1 < KT) STAGE(buf^1, (kt+1)*32);

    f16x8 af[4], bf[4];
    #pragma unroll
    for(int mt=0;mt<4;mt++)
      af[mt] = *(f16x8*)&Ah[buf][(wm*64 + mt*16 + fr)*32 + kq*8];
    #pragma unroll
    for(int nt=0;nt<4;nt++)
      bf[nt] = *(f16x8*)&Bh[buf][(wn*64 + nt*16 + fr)*32 + kq*8];
    #pragma unroll
    for(int mt=0;mt<4;mt++)
      #pragma unroll
      for(int nt=0;nt<4;nt++)
        acc[mt][nt] = __builtin_amdgcn_mfma_f32_16x16x32_f16(af[mt], bf[nt], acc[mt][nt], 0,0,0);
    __syncthreads();
    buf ^= 1;
  }
#undef STAGE

  // epilogue: col = bn0+wn*64+nt*16+fr, row = bm0+wm*64+mt*16+kq*4+r
  #pragma unroll
  for(int nt=0;nt<4;nt++){
    const int col = bn0 + wn*64 + nt*16 + fr;
    const float bb = biasp[col];
    #pragma unroll
    for(int mt=0;mt<4;mt++){
      #pragma unroll
      for(int r=0;r<4;r++){
        const size_t row = bm0 + wm*64 + mt*16 + kq*4 + r;
        float v = acc[mt][nt][r] + bb;
        if(EPI==1) v = gelu_f(v);
        if(EPI==2) v += res[row*N + col];
        if(OB) ((h16*)Cv)[(size_t)z*zC + row*N + col] = (h16)v;
        else   ((float*)Cv)[(size_t)z*zC + row*N + col] = v;
      }
    }
  }
}

// ======================= MFMA flash attention (f16, rope fused in staging) =======================
// grid (T/64, CB*NH), 256 thr = 4 waves; wave w owns q rows w*16..w*16+15 of the 64-row Q tile.
// Swapped QK^T: S^T = mfma(K, Q) so softmax state is lane-scalar (q = lane&15).
__global__ __launch_bounds__(256,4) void attn_mfma_kernel(
    const h16* __restrict__ qg, const h16* __restrict__ kg,
    const h16* __restrict__ vg, h16* __restrict__ og,
    const float* __restrict__ cost, const float* __restrict__ sint)
{
  __shared__ __align__(16) h16 Q_lds[64][72];
  __shared__ __align__(16) h16 K_lds[64][72];
  __shared__ __align__(16) h16 Vt[64][72];    // Vt[d][k]
  __shared__ __align__(16) h16 P_lds[64][72]; // P[q][k]

  const int qt = blockIdx.x;
  const int bh = blockIdx.y;
  const int b = bh >> 4, h = bh & 15;
  const int tid = threadIdx.x;
  const int wid = tid >> 6, lane = tid & 63;
  const size_t base = ((size_t)b*T_)*H_ + (size_t)h*HD_;

  const int srow = tid >> 2;        // 0..63
  const int sc8  = (tid & 3) * 8;   // 0,8,16,24 (first-half d)
  const int sc16 = (tid & 3) * 16;  // V staging col base

  // --- stage Q with rope + 1/sqrt(64) scale ---
  {
    const int t = qt*64 + srow;
    const h16* qp = qg + base + (size_t)t*H_;
    f16x8 lo = *(const f16x8*)(qp + sc8);
    f16x8 hi = *(const f16x8*)(qp + sc8 + 32);
    float cc[8], ss[8];
    *(float4*)&cc[0] = *(const float4*)(cost + t*32 + sc8);
    *(float4*)&cc[4] = *(const float4*)(cost + t*32 + sc8 + 4);
    *(float4*)&ss[0] = *(const float4*)(sint + t*32 + sc8);
    *(float4*)&ss[4] = *(const float4*)(sint + t*32 + sc8 + 4);
    f16x8 olo, ohi;
    #pragma unroll
    for(int j=0;j<8;j++){
      const float x0 = (float)lo[j], x1 = (float)hi[j];
      olo[j] = (h16)((x0*cc[j] - x1*ss[j])*0.125f);
      ohi[j] = (h16)((x1*cc[j] + x0*ss[j])*0.125f);
    }
    *(f16x8*)&Q_lds[srow][sc8]    = olo;
    *(f16x8*)&Q_lds[srow][sc8+32] = ohi;
  }

  const int fr = lane & 15;   // this lane's q slot (within wave tile) / frag col
  const int g  = lane >> 4;   // lane group
  const int wq0 = wid * 16;

  float m_run = -1e30f, l_run = 0.f;
  f32x4 acc[4];
  #pragma unroll
  for(int i=0;i<4;i++) acc[i] = (f32x4){0.f,0.f,0.f,0.f};

  for(int kt=0; kt<T_/64; kt++){
    __syncthreads();   // all waves done reading K/Vt (first iter: Q staged)
    // --- stage K (rope) + V (transposed) ---
    {
      const int t = kt*64 + srow;
      const h16* kp = kg + base + (size_t)t*H_;
      f16x8 lo = *(const f16x8*)(kp + sc8);
      f16x8 hi = *(const f16x8*)(kp + sc8 + 32);
      float cc[8], ss[8];
      *(float4*)&cc[0] = *(const float4*)(cost + t*32 + sc8);
      *(float4*)&cc[4] = *(const float4*)(cost + t*32 + sc8 + 4);
      *(float4*)&ss[0] = *(const float4*)(sint + t*32 + sc8);
      *(float4*)&ss[4] = *(const float4*)(sint + t*32 + sc8 + 4);
      f16x8 olo, ohi;
      #pragma unroll
      for(int j=0;j<8;j++){
        const float x0 = (float)lo[j], x1 = (float)hi[j];
        olo[j] = (h16)(x0*cc[j] - x1*ss[j]);
        ohi[j] = (h16)(x1*cc[j] + x0*ss[j]);
      }
      *(f16x8*)&K_lds[srow][sc8]    = olo;
      *(f16x8*)&K_lds[srow][sc8+32] = ohi;

      const h16* vp = vg + base + (size_t)t*H_;
      f16x8 v0 = *(const f16x8*)(vp + sc16);
      f16x8 v1 = *(const f16x8*)(vp + sc16 + 8);
      #pragma unroll
      for(int j=0;j<8;j++){
        Vt[sc16+j][srow]   = v0[j];
        Vt[sc16+8+j][srow] = v1[j];
      }
    }
    __syncthreads();

    // --- S^T frags: sfr[mt] covers k rows mt*16..+15 for this wave's 16 q cols ---
    f32x4 sfr[4];
    #pragma unroll
    for(int mt=0;mt<4;mt++) sfr[mt] = (f32x4){0.f,0.f,0.f,0.f};
    #pragma unroll
    for(int kk=0;kk<2;kk++){
      const f16x8 qf = *(f16x8*)&Q_lds[wq0 + fr][kk*32 + g*8];
      #pragma unroll
      for(int mt=0;mt<4;mt++){
        const f16x8 kf = *(f16x8*)&K_lds[mt*16 + fr][kk*32 + g*8];
        sfr[mt] = __builtin_amdgcn_mfma_f32_16x16x32_f16(kf, qf, sfr[mt], 0,0,0);
      }
    }

    // --- online softmax (state per lane; q = wq0+fr) ---
    float tmax = -1e30f;
    #pragma unroll
    for(int mt=0;mt<4;mt++)
      #pragma unroll
      for(int r=0;r<4;r++) tmax = fmaxf(tmax, sfr[mt][r]);
    tmax = fmaxf(tmax, __shfl_xor(tmax, 16));
    tmax = fmaxf(tmax, __shfl_xor(tmax, 32));
    const float mn = fmaxf(m_run, tmax);
    const float alpha = __expf(m_run - mn);
    m_run = mn;
    float psum = 0.f;
    h16 pb[4][4];
    #pragma unroll
    for(int mt=0;mt<4;mt++)
      #pragma unroll
      for(int r=0;r<4;r++){
        const h16 ph = (h16)__expf(sfr[mt][r] - mn);
        pb[mt][r] = ph;
        psum += (float)ph;
      }
    psum += __shfl_xor(psum, 16);
    psum += __shfl_xor(psum, 32);
    l_run = l_run*alpha + psum;

    // write P rows (own wave rows only; same-wave LDS RAW ordered by compiler)
    #pragma unroll
    for(int mt=0;mt<4;mt++)
      *(f16x4*)&P_lds[wq0 + fr][mt*16 + g*4] = *(f16x4*)pb[mt];

    // rescale O acc by per-row alpha (acc rows are q = wq0 + 4g + r)
    float a_r[4];
    #pragma unroll
    for(int r=0;r<4;r++) a_r[r] = __shfl(alpha, (lane & 48) | (4*g + r));
    #pragma unroll
    for(int nt=0;nt<4;nt++)
      #pragma unroll
      for(int r=0;r<4;r++) acc[nt][r] *= a_r[r];

    // --- PV: acc[nt] += P[q][k] @ V[k][d] ---
    #pragma unroll
    for(int kk=0;kk<2;kk++){
      const f16x8 pf = *(f16x8*)&P_lds[wq0 + fr][kk*32 + g*8];
      #pragma unroll
      for(int nt=0;nt<4;nt++){
        const f16x8 vf = *(f16x8*)&Vt[nt*16 + fr][kk*32 + g*8];
        acc[nt] = __builtin_amdgcn_mfma_f32_16x16x32_f16(pf, vf, acc[nt], 0,0,0);
      }
    }
  }

  // --- epilogue: O row q = wq0+4g+r, col d = nt*16+fr ---
  float linv[4];
  #pragma unroll
  for(int r=0;r<4;r++) linv[r] = 1.0f / __shfl(l_run, (lane & 48) | (4*g + r));
  #pragma unroll
  for(int nt=0;nt<4;nt++){
    const int d = nt*16 + fr;
    #pragma unroll
    for(int r=0;r<4;r++){
      const int t = qt*64 + wq0 + 4*g + r;
      og[base + (size_t)t*H_ + d] = (h16)(acc[nt][r] * linv[r]);
    }
  }
}

// ======================= launch =======================
extern "C" void kernel_launch(void* const* d_in, const int* in_sizes, int n_in,
                              void* d_out, int out_size, void* d_ws, size_t ws_size,
                              hipStream_t stream)
{
  const float* x   = (const float*)d_in[0];
  const float* Wq  = (const float*)d_in[1];
  const float* bq  = (const float*)d_in[2];
  const float* Wk  = (const float*)d_in[3];
  const float* bk  = (const float*)d_in[4];
  const float* Wv  = (const float*)d_in[5];
  const float* bv  = (const float*)d_in[6];
  const float* Wo  = (const float*)d_in[7];
  const float* bo  = (const float*)d_in[8];
  const float* g1  = (const float*)d_in[9];
  const float* be1 = (const float*)d_in[10];
  const float* g2  = (const float*)d_in[11];
  const float* be2 = (const float*)d_in[12];
  const float* W1  = (const float*)d_in[13];
  const float* b1  = (const float*)d_in[14];
  const float* W2  = (const float*)d_in[15];
  const float* b2  = (const float*)d_in[16];
  float* out = (float*)d_out;
  char*  W   = (char*)d_ws;

  // ws layout (bytes), total ~88.3 MiB (proven budget: 112.4 MiB)
  h16* wqkv = (h16*)(W + 0*MB_);     // [3][1024][1024] f16
  h16* wo   = (h16*)(W + 6*MB_);     // [1024][1024]
  h16* w1   = (h16*)(W + 8*MB_);     // [4096][1024]
  h16* w2   = (h16*)(W + 16*MB_);    // [1024][4096]
  h16* abuf = (h16*)(W + 24*MB_);    // [BT][H] f16 attn-out; FFN h chunk aliases
  h16* hb   = abuf;                  // [CR][FF] f16 = 32MB
  h16* qkvc = (h16*)(W + 56*MB_);    // [3][CR][H] f16
  h16* xnc  = (h16*)(W + 80*MB_);    // [CR][H] f16 LN'd activations (reused)
  float* cost = (float*)(W + 88*MB_);   // [T][32]
  float* sint = cost + T_*32;           // [T][32]
  float* bqkv = sint + T_*32;           // [3][H]

  const size_t CRH = (size_t)CR_ * H_;

  rope_table_kernel<<<T_, 32, 0, stream>>>(cost, sint);
  concat3_kernel<<<(3*H_+255)/256, 256, 0, stream>>>(bq, bk, bv, bqkv);

  // weight transpose+convert (f16, [N][K])
  tcvt_kernel<<<dim3(32,32),  256, 0, stream>>>(Wq, wqkv,              H_, H_);
  tcvt_kernel<<<dim3(32,32),  256, 0, stream>>>(Wk, wqkv + 1024*1024,  H_, H_);
  tcvt_kernel<<<dim3(32,32),  256, 0, stream>>>(Wv, wqkv + 2*1024*1024,H_, H_);
  tcvt_kernel<<<dim3(32,32),  256, 0, stream>>>(Wo, wo, H_, H_);
  tcvt_kernel<<<dim3(128,32), 256, 0, stream>>>(W1, w1, H_, FF_);
  tcvt_kernel<<<dim3(32,128), 256, 0, stream>>>(W2, w2, FF_, H_);

  // QKV + attention (rope fused in attn staging), chunked over 4 groups of 8 batches
  for(int c=0; c<NC_; c++){
    const size_t r0 = (size_t)c * CR_;
    ln_f16_kernel<<<CR_, 256, 0, stream>>>(x + r0*H_, g1, be1, xnc);
    gemm_f16<0,1><<<dim3(8, CR_/128, 3), 256, 0, stream>>>(
        xnc, wqkv, bqkv, nullptr, qkvc, CR_, H_, H_,
        (size_t)1024*1024, CRH, H_);
    attn_mfma_kernel<<<dim3(T_/64, CB_*NH_), 256, 0, stream>>>(
        qkvc, qkvc + CRH, qkvc + 2*CRH, abuf + r0*H_, cost, sint);
  }

  // x2 = x + attn @ Wo + bo   -> d_out (fp32)
  gemm_f16<2,0><<<dim3(8, BT_/128, 1), 256, 0, stream>>>(
      abuf, wo, bo, x, out, BT_, H_, H_, 0, 0, 0);

  // FFN in 4 row-chunks of CR_ (h f16 chunk aliases abuf, dead after Wo GEMM)
  for(int c=0; c<NC_; c++){
    const size_t r0 = (size_t)c * CR_;
    ln_f16_kernel<<<CR_, 256, 0, stream>>>(out + r0*H_, g2, be2, xnc);
    gemm_f16<1,1><<<dim3(FF_/128, CR_/128, 1), 256, 0, stream>>>(
        xnc, w1, b1, nullptr, hb, CR_, FF_, H_, 0, 0, 0);
    gemm_f16<2,0><<<dim3(H_/128, CR_/128, 1), 256, 0, stream>>>(
        hb, w2, b2, out + r0*H_, out + r0*H_, CR_, H_, FF_, 0, 0, 0);
  }
}